// Round 14
// baseline (65068.042 us; speedup 1.0000x reference)
//
#include <hip/hip_runtime.h>
#include <math.h>

typedef float v2f __attribute__((ext_vector_type(2)));

#define EPSV 1e-5f
#define SBAR() __builtin_amdgcn_sched_barrier(0)

// Cross-lane within a 4-lane quad via DPP quad_perm (pure VALU, 1 cyc).
template <int CTRL>
__device__ __forceinline__ float qp(float x) {
  return __int_as_float(
      __builtin_amdgcn_update_dpp(0, __float_as_int(x), CTRL, 0xF, 0xF, true));
}
#define XOR1(x) qp<0xB1>(x)   // quad_perm [1,0,3,2]
#define XOR2(x) qp<0x4E>(x)   // quad_perm [2,3,0,1]
#define XOR3(x) qp<0x1B>(x)   // quad_perm [3,2,1,0]

// Weights staged with algebraic folds (R13) + row remap for W2/G3.
// R14: each quad serves TWO systems -> every ds_read_b128 feeds both
// (halves LDS-pipe instructions per CU-eval, the R13 wall).
struct __align__(16) WS {
  float W1[128]; float b1[32]; float W2[128]; float b2[4];
  float G1[128]; float gb1[32];
  float G2[1024]; float gb2[32];
  float G3[128]; float gb3[4];
};

// packed a += s * {wx,wy} -> v_pk_fma_f32. v2f ONLY as named locals (R6 lesson).
__device__ __forceinline__ v2f pkfma(float s, float wx, float wy, v2f a) {
  v2f w = {wx, wy};
  v2f sv = {s, s};
  return __builtin_elementwise_fma(sv, w, a);
}

// tanh from PRE-SCALED arg a = 2*log2(e)*x: tanh(x)=1-2/(exp2(a)+1).
__device__ __forceinline__ float ftanhp(float a) {
  float e = __builtin_amdgcn_exp2f(a);
  float r = __builtin_amdgcn_rcpf(e + 1.0f);
  return fmaf(-2.0f, r, 1.0f);
}

// Pure normalize over 32 values held 8-per-lane across a quad (DPP reduce).
__device__ __forceinline__ void lnz8_quad(float* t) {
  float s = 0.f, ss = 0.f;
  #pragma unroll
  for (int i = 0; i < 8; ++i) { s += t[i]; ss = fmaf(t[i], t[i], ss); }
  s += XOR1(s);  ss += XOR1(ss);
  s += XOR2(s);  ss += XOR2(ss);
  float m = s * 0.03125f;
  float v = fmaf(-m, m, ss * 0.03125f);
  float r = __frsqrt_rn(v + EPSV);
  float nmr = -m * r;
  #pragma unroll
  for (int i = 0; i < 8; ++i) t[i] = fmaf(t[i], r, nmr);
}

// f-eval for TWO systems on one 4-lane quad: lane p owns cols [8p,8p+8) of
// each 32-wide layer for BOTH systems; each weight read is used twice.
__device__ __forceinline__ void fode4x2(const WS* w, int p,
                                        const float yA[4], const float yB[4],
                                        float outA[4], float outB[4]) {
  const float4* W1v  = (const float4*)w->W1;
  const float4* b1v  = (const float4*)w->b1;
  const float4* W2v  = (const float4*)w->W2;   // row-remapped
  const float4* G1v  = (const float4*)w->G1;
  const float4* gb1v = (const float4*)w->gb1;
  const float4* G2v  = (const float4*)w->G2;
  const float4* gb2v = (const float4*)w->gb2;
  const float4* G3v  = (const float4*)w->G3;   // row-remapped, l2g-scaled
  const int j0 = 2 * p;   // my float4 col-group base (of 8)
  const int r0 = 8 * p;   // my row base (of 32)

  // ---- magnitude net ----
  v2f mA0 = {0.f,0.f}, mA1 = {0.f,0.f}, mB0 = {0.f,0.f}, mB1 = {0.f,0.f};
  #pragma unroll
  for (int j = 0; j < 2; ++j) {
    float4 bb = b1v[j0 + j];
    v2f aA0 = {bb.x, bb.y}, aA1 = {bb.z, bb.w};
    v2f aB0 = {bb.x, bb.y}, aB1 = {bb.z, bb.w};
    #pragma unroll
    for (int i = 0; i < 4; ++i) {
      float4 wv = W1v[i * 8 + j0 + j];
      aA0 = pkfma(yA[i], wv.x, wv.y, aA0); aA1 = pkfma(yA[i], wv.z, wv.w, aA1);
      aB0 = pkfma(yB[i], wv.x, wv.y, aB0); aB1 = pkfma(yB[i], wv.z, wv.w, aB1);
    }
    SBAR();
    float hA0 = ftanhp(aA0.x), hA1 = ftanhp(aA0.y);
    float hA2 = ftanhp(aA1.x), hA3 = ftanhp(aA1.y);
    float hB0 = ftanhp(aB0.x), hB1 = ftanhp(aB0.y);
    float hB2 = ftanhp(aB1.x), hB3 = ftanhp(aB1.y);
    float4 w0 = W2v[(4*j + 0) * 4 + p];
    mA0 = pkfma(hA0, w0.x, w0.y, mA0); mA1 = pkfma(hA0, w0.z, w0.w, mA1);
    mB0 = pkfma(hB0, w0.x, w0.y, mB0); mB1 = pkfma(hB0, w0.z, w0.w, mB1);
    float4 w1 = W2v[(4*j + 1) * 4 + p];
    mA0 = pkfma(hA1, w1.x, w1.y, mA0); mA1 = pkfma(hA1, w1.z, w1.w, mA1);
    mB0 = pkfma(hB1, w1.x, w1.y, mB0); mB1 = pkfma(hB1, w1.z, w1.w, mB1);
    float4 w2 = W2v[(4*j + 2) * 4 + p];
    mA0 = pkfma(hA2, w2.x, w2.y, mA0); mA1 = pkfma(hA2, w2.z, w2.w, mA1);
    mB0 = pkfma(hB2, w2.x, w2.y, mB0); mB1 = pkfma(hB2, w2.z, w2.w, mB1);
    float4 w3 = W2v[(4*j + 3) * 4 + p];
    mA0 = pkfma(hA3, w3.x, w3.y, mA0); mA1 = pkfma(hA3, w3.z, w3.w, mA1);
    mB0 = pkfma(hB3, w3.x, w3.y, mB0); mB1 = pkfma(hB3, w3.z, w3.w, mB1);
    SBAR();
  }

  // ---- gating layer 1 ----
  float tmA[8], tmB[8];
  #pragma unroll
  for (int j = 0; j < 2; ++j) {
    float4 bb = gb1v[j0 + j];
    v2f aA0 = {bb.x, bb.y}, aA1 = {bb.z, bb.w};
    v2f aB0 = {bb.x, bb.y}, aB1 = {bb.z, bb.w};
    #pragma unroll
    for (int i = 0; i < 4; ++i) {
      float4 wv = G1v[i * 8 + j0 + j];
      aA0 = pkfma(yA[i], wv.x, wv.y, aA0); aA1 = pkfma(yA[i], wv.z, wv.w, aA1);
      aB0 = pkfma(yB[i], wv.x, wv.y, aB0); aB1 = pkfma(yB[i], wv.z, wv.w, aB1);
    }
    tmA[4*j+0] = ftanhp(aA0.x); tmA[4*j+1] = ftanhp(aA0.y);
    tmA[4*j+2] = ftanhp(aA1.x); tmA[4*j+3] = ftanhp(aA1.y);
    tmB[4*j+0] = ftanhp(aB0.x); tmB[4*j+1] = ftanhp(aB0.y);
    tmB[4*j+2] = ftanhp(aB1.x); tmB[4*j+3] = ftanhp(aB1.y);
    SBAR();
  }
  lnz8_quad(tmA);
  lnz8_quad(tmB);

  // ---- gating layer 2: weight reads shared by both systems ----
  float umA[8], umB[8];
  {
    float4 bb0 = gb2v[j0], bb1 = gb2v[j0 + 1];
    v2f aA00 = {bb0.x, bb0.y}, aA01 = {bb0.z, bb0.w};
    v2f aA10 = {bb1.x, bb1.y}, aA11 = {bb1.z, bb1.w};
    v2f aB00 = {bb0.x, bb0.y}, aB01 = {bb0.z, bb0.w};
    v2f aB10 = {bb1.x, bb1.y}, aB11 = {bb1.z, bb1.w};

#define G2_GROUP(RQ, GA, GB)                                            \
    _Pragma("unroll")                                                   \
    for (int i = 0; i < 8; ++i) {                                       \
      float sA = (GA); float sB = (GB);                                 \
      float4 w0 = G2v[((RQ) + i) * 8 + j0];                             \
      aA00 = pkfma(sA, w0.x, w0.y, aA00); aA01 = pkfma(sA, w0.z, w0.w, aA01); \
      aB00 = pkfma(sB, w0.x, w0.y, aB00); aB01 = pkfma(sB, w0.z, w0.w, aB01); \
      float4 w1 = G2v[((RQ) + i) * 8 + j0 + 1];                         \
      aA10 = pkfma(sA, w1.x, w1.y, aA10); aA11 = pkfma(sA, w1.z, w1.w, aA11); \
      aB10 = pkfma(sB, w1.x, w1.y, aB10); aB11 = pkfma(sB, w1.z, w1.w, aB11); \
      if (i == 3) SBAR();                                               \
    }                                                                   \
    SBAR();

    G2_GROUP(r0,        tmA[i],        tmB[i])
    G2_GROUP(r0 ^ 8,    XOR1(tmA[i]),  XOR1(tmB[i]))
    G2_GROUP(r0 ^ 16,   XOR2(tmA[i]),  XOR2(tmB[i]))
    G2_GROUP(r0 ^ 24,   XOR3(tmA[i]),  XOR3(tmB[i]))
#undef G2_GROUP

    umA[0] = ftanhp(aA00.x); umA[1] = ftanhp(aA00.y);
    umA[2] = ftanhp(aA01.x); umA[3] = ftanhp(aA01.y);
    umA[4] = ftanhp(aA10.x); umA[5] = ftanhp(aA10.y);
    umA[6] = ftanhp(aA11.x); umA[7] = ftanhp(aA11.y);
    umB[0] = ftanhp(aB00.x); umB[1] = ftanhp(aB00.y);
    umB[2] = ftanhp(aB01.x); umB[3] = ftanhp(aB01.y);
    umB[4] = ftanhp(aB10.x); umB[5] = ftanhp(aB10.y);
    umB[6] = ftanhp(aB11.x); umB[7] = ftanhp(aB11.y);
  }
  lnz8_quad(umA);
  lnz8_quad(umB);

  // ---- G3' partials over my 8 rows, then quad-reduce (DPP) ----
  v2f zA0 = {0.f,0.f}, zA1 = {0.f,0.f}, zB0 = {0.f,0.f}, zB1 = {0.f,0.f};
  #pragma unroll
  for (int i = 0; i < 8; ++i) {
    float4 wv = G3v[i * 4 + p];   // remapped slot for row 8p+i
    zA0 = pkfma(umA[i], wv.x, wv.y, zA0); zA1 = pkfma(umA[i], wv.z, wv.w, zA1);
    zB0 = pkfma(umB[i], wv.x, wv.y, zB0); zB1 = pkfma(umB[i], wv.z, wv.w, zB1);
    if (i == 3) SBAR();
  }
  SBAR();

  const float NL2E = -1.4426950408889634f;  // -log2(e)
  float4 b2v  = *(const float4*)w->b2;
  float4 gb3v = *(const float4*)w->gb3;
  {
    float zx = zA0.x, zy = zA0.y, zz = zA1.x, zw = zA1.y;
    float mx = mA0.x, my = mA0.y, mz = mA1.x, mw = mA1.y;
    zx += XOR1(zx); zx += XOR2(zx);
    zy += XOR1(zy); zy += XOR2(zy);
    zz += XOR1(zz); zz += XOR2(zz);
    zw += XOR1(zw); zw += XOR2(zw);
    mx += XOR1(mx); mx += XOR2(mx);
    my += XOR1(my); my += XOR2(my);
    mz += XOR1(mz); mz += XOR2(mz);
    mw += XOR1(mw); mw += XOR2(mw);
    zx += gb3v.x; zy += gb3v.y; zz += gb3v.z; zw += gb3v.w;
    outA[0] = (mx + b2v.x) * __builtin_amdgcn_exp2f(NL2E * zx * zx);
    outA[1] = (my + b2v.y) * __builtin_amdgcn_exp2f(NL2E * zy * zy);
    outA[2] = (mz + b2v.z) * __builtin_amdgcn_exp2f(NL2E * zz * zz);
    outA[3] = (mw + b2v.w) * __builtin_amdgcn_exp2f(NL2E * zw * zw);
  }
  {
    float zx = zB0.x, zy = zB0.y, zz = zB1.x, zw = zB1.y;
    float mx = mB0.x, my = mB0.y, mz = mB1.x, mw = mB1.y;
    zx += XOR1(zx); zx += XOR2(zx);
    zy += XOR1(zy); zy += XOR2(zy);
    zz += XOR1(zz); zz += XOR2(zz);
    zw += XOR1(zw); zw += XOR2(zw);
    mx += XOR1(mx); mx += XOR2(mx);
    my += XOR1(my); my += XOR2(my);
    mz += XOR1(mz); mz += XOR2(mz);
    mw += XOR1(mw); mw += XOR2(mw);
    zx += gb3v.x; zy += gb3v.y; zz += gb3v.z; zw += gb3v.w;
    outB[0] = (mx + b2v.x) * __builtin_amdgcn_exp2f(NL2E * zx * zx);
    outB[1] = (my + b2v.y) * __builtin_amdgcn_exp2f(NL2E * zy * zy);
    outB[2] = (mz + b2v.z) * __builtin_amdgcn_exp2f(NL2E * zz * zz);
    outB[3] = (mw + b2v.w) * __builtin_amdgcn_exp2f(NL2E * zw * zw);
  }
}

// waves_per_eu(2,2): demand ~140 VGPR; pin occupancy at exactly 2 waves/EU so
// the allocator does NOT squeeze to 128 and re-spill (R10 trap).
__global__ __launch_bounds__(256)
__attribute__((amdgpu_waves_per_eu(2, 2))) void ode_kernel(
    const float* __restrict__ s_grid, const float* __restrict__ y0,
    const float* __restrict__ W1, const float* __restrict__ b1,
    const float* __restrict__ W2, const float* __restrict__ b2,
    const float* __restrict__ G1, const float* __restrict__ gb1,
    const float* __restrict__ l1g, const float* __restrict__ l1b,
    const float* __restrict__ G2, const float* __restrict__ gb2,
    const float* __restrict__ l2g, const float* __restrict__ l2b,
    const float* __restrict__ G3, const float* __restrict__ gb3,
    float* __restrict__ out, int T, int B) {
  __shared__ WS w;
  __shared__ float sg[512];
  const int tx = threadIdx.x;
  const float TL2E = 2.8853900817779268f;   // 2*log2(e)

  for (int i = tx; i < 128; i += 256) {
    w.W1[i] = W1[i] * TL2E;
    w.G1[i] = G1[i] * TL2E;
  }
  for (int i = tx; i < 1024; i += 256) w.G2[i] = G2[i] * l1g[i >> 5] * TL2E;
  if (tx < 32) {
    const int d = (tx & 7) * 4 + (tx >> 3);   // row remap
    ((float4*)w.W2)[d] = ((const float4*)W2)[tx];
    float4 g3 = ((const float4*)G3)[tx];
    const float s3 = l2g[tx];
    g3.x *= s3; g3.y *= s3; g3.z *= s3; g3.w *= s3;
    ((float4*)w.G3)[d] = g3;
    w.b1[tx]  = b1[tx]  * TL2E;
    w.gb1[tx] = gb1[tx] * TL2E;
    float acc = gb2[tx];
    for (int r = 0; r < 32; ++r) acc = fmaf(l1b[r], G2[r * 32 + tx], acc);
    w.gb2[tx] = acc * TL2E;
  }
  if (tx < 4) {
    w.b2[tx] = b2[tx];
    float acc = gb3[tx];
    for (int r = 0; r < 32; ++r) acc = fmaf(l2b[r], G3[r * 4 + tx], acc);
    w.gb3[tx] = acc;
  }
  for (int i = tx; i < T && i < 512; i += 256) sg[i] = s_grid[i];
  __syncthreads();

  const int tid  = blockIdx.x * 256 + tx;
  const int quad = tid >> 2;       // one quad serves TWO systems
  const int p    = tid & 3;
  const int sA   = 2 * quad;
  if (sA + 1 >= B + 1) return;     // B even

  float4 yA0 = ((const float4*)y0)[sA];
  float4 yB0 = ((const float4*)y0)[sA + 1];
  float yA[4] = {yA0.x, yA0.y, yA0.z, yA0.w};
  float yB[4] = {yB0.x, yB0.y, yB0.z, yB0.w};

  // lane p stores component p of each system; flat idx = t*4B + 8*quad + p (+4)
  {
    const size_t base = (size_t)8 * quad + p;
    float a = (p == 0) ? yA[0] : ((p == 1) ? yA[1] : ((p == 2) ? yA[2] : yA[3]));
    float b = (p == 0) ? yB[0] : ((p == 1) ? yB[1] : ((p == 2) ? yB[2] : yB[3]));
    out[base] = a;
    out[base + 4] = b;
  }

  #pragma unroll 1
  for (int t = 0; t < T - 1; ++t) {
    const float h = sg[t + 1] - sg[t];
    float kA[4], kB[4], ksA[4], ksB[4], ytA[4], ytB[4];

    fode4x2(&w, p, yA, yB, kA, kB);
    #pragma unroll
    for (int c = 0; c < 4; ++c) {
      ksA[c] = kA[c]; ytA[c] = fmaf(0.5f * h, kA[c], yA[c]);
      ksB[c] = kB[c]; ytB[c] = fmaf(0.5f * h, kB[c], yB[c]);
    }
    SBAR();
    fode4x2(&w, p, ytA, ytB, kA, kB);
    #pragma unroll
    for (int c = 0; c < 4; ++c) {
      ksA[c] = fmaf(2.0f, kA[c], ksA[c]); ytA[c] = fmaf(0.5f * h, kA[c], yA[c]);
      ksB[c] = fmaf(2.0f, kB[c], ksB[c]); ytB[c] = fmaf(0.5f * h, kB[c], yB[c]);
    }
    SBAR();
    fode4x2(&w, p, ytA, ytB, kA, kB);
    #pragma unroll
    for (int c = 0; c < 4; ++c) {
      ksA[c] = fmaf(2.0f, kA[c], ksA[c]); ytA[c] = fmaf(h, kA[c], yA[c]);
      ksB[c] = fmaf(2.0f, kB[c], ksB[c]); ytB[c] = fmaf(h, kB[c], yB[c]);
    }
    SBAR();
    fode4x2(&w, p, ytA, ytB, kA, kB);
    #pragma unroll
    for (int c = 0; c < 4; ++c) {
      yA[c] = fmaf(h * (1.0f / 6.0f), ksA[c] + kA[c], yA[c]);
      yB[c] = fmaf(h * (1.0f / 6.0f), ksB[c] + kB[c], yB[c]);
    }

    const size_t base = (size_t)(t + 1) * 4 * B + (size_t)8 * quad + p;
    float a = (p == 0) ? yA[0] : ((p == 1) ? yA[1] : ((p == 2) ? yA[2] : yA[3]));
    float b = (p == 0) ? yB[0] : ((p == 1) ? yB[1] : ((p == 2) ? yB[2] : yB[3]));
    out[base] = a;
    out[base + 4] = b;
  }
}

extern "C" void kernel_launch(void* const* d_in, const int* in_sizes, int n_in,
                              void* d_out, int out_size, void* d_ws, size_t ws_size,
                              hipStream_t stream) {
  const float* s_grid = (const float*)d_in[0];
  const float* y0     = (const float*)d_in[1];
  const float* W1     = (const float*)d_in[2];
  const float* b1     = (const float*)d_in[3];
  const float* W2     = (const float*)d_in[4];
  const float* b2     = (const float*)d_in[5];
  const float* G1     = (const float*)d_in[6];
  const float* gb1    = (const float*)d_in[7];
  const float* l1g    = (const float*)d_in[8];
  const float* l1b    = (const float*)d_in[9];
  const float* G2     = (const float*)d_in[10];
  const float* gb2    = (const float*)d_in[11];
  const float* l2g    = (const float*)d_in[12];
  const float* l2b    = (const float*)d_in[13];
  const float* G3     = (const float*)d_in[14];
  const float* gb3    = (const float*)d_in[15];

  const int T = in_sizes[0];
  const int B = in_sizes[1] / 4;

  const long long threads = 2LL * B;   // 4 lanes per 2 systems
  dim3 block(256);
  dim3 grid((unsigned)((threads + 255) / 256));
  hipLaunchKernelGGL(ode_kernel, grid, block, 0, stream,
                     s_grid, y0, W1, b1, W2, b2, G1, gb1, l1g, l1b,
                     G2, gb2, l2g, l2b, G3, gb3, (float*)d_out, T, B);
}

// Round 15
// 46123.703 us; speedup vs baseline: 1.4107x; 1.4107x over previous
//
#include <hip/hip_runtime.h>
#include <math.h>

typedef float v2f __attribute__((ext_vector_type(2)));

#define EPSV 1e-5f
#define SBAR() __builtin_amdgcn_sched_barrier(0)

// Cross-lane within a 4-lane quad via DPP quad_perm (pure VALU, 1 cyc).
template <int CTRL>
__device__ __forceinline__ float qp(float x) {
  return __int_as_float(
      __builtin_amdgcn_update_dpp(0, __float_as_int(x), CTRL, 0xF, 0xF, true));
}
#define XOR1(x) qp<0xB1>(x)   // quad_perm [1,0,3,2]
#define XOR2(x) qp<0x4E>(x)   // quad_perm [2,3,0,1]
#define XOR3(x) qp<0x1B>(x)   // quad_perm [3,2,1,0]

// Weights staged with algebraic folds (R13) + row remap for W2/G3.
// Each quad serves TWO systems -> every ds_read_b128 feeds both
// (halves LDS-pipe instructions per CU-eval, the R13 wall).
struct __align__(16) WS {
  float W1[128]; float b1[32]; float W2[128]; float b2[4];
  float G1[128]; float gb1[32];
  float G2[1024]; float gb2[32];
  float G3[128]; float gb3[4];
};

// packed a += s * {wx,wy} -> v_pk_fma_f32. v2f ONLY as named locals (R6 lesson).
__device__ __forceinline__ v2f pkfma(float s, float wx, float wy, v2f a) {
  v2f w = {wx, wy};
  v2f sv = {s, s};
  return __builtin_elementwise_fma(sv, w, a);
}

// tanh from PRE-SCALED arg a = 2*log2(e)*x: tanh(x)=1-2/(exp2(a)+1).
__device__ __forceinline__ float ftanhp(float a) {
  float e = __builtin_amdgcn_exp2f(a);
  float r = __builtin_amdgcn_rcpf(e + 1.0f);
  return fmaf(-2.0f, r, 1.0f);
}

// Pure normalize over 32 values held 8-per-lane across a quad (DPP reduce).
__device__ __forceinline__ void lnz8_quad(float* t) {
  float s = 0.f, ss = 0.f;
  #pragma unroll
  for (int i = 0; i < 8; ++i) { s += t[i]; ss = fmaf(t[i], t[i], ss); }
  s += XOR1(s);  ss += XOR1(ss);
  s += XOR2(s);  ss += XOR2(ss);
  float m = s * 0.03125f;
  float v = fmaf(-m, m, ss * 0.03125f);
  float r = __frsqrt_rn(v + EPSV);
  float nmr = -m * r;
  #pragma unroll
  for (int i = 0; i < 8; ++i) t[i] = fmaf(t[i], r, nmr);
}

// f-eval for TWO systems on one 4-lane quad: lane p owns cols [8p,8p+8) of
// each 32-wide layer for BOTH systems; each weight read is used twice.
__device__ __forceinline__ void fode4x2(const WS* w, int p,
                                        const float yA[4], const float yB[4],
                                        float outA[4], float outB[4]) {
  const float4* W1v  = (const float4*)w->W1;
  const float4* b1v  = (const float4*)w->b1;
  const float4* W2v  = (const float4*)w->W2;   // row-remapped
  const float4* G1v  = (const float4*)w->G1;
  const float4* gb1v = (const float4*)w->gb1;
  const float4* G2v  = (const float4*)w->G2;
  const float4* gb2v = (const float4*)w->gb2;
  const float4* G3v  = (const float4*)w->G3;   // row-remapped, l2g-scaled
  const int j0 = 2 * p;   // my float4 col-group base (of 8)
  const int r0 = 8 * p;   // my row base (of 32)

  // ---- magnitude net ----
  v2f mA0 = {0.f,0.f}, mA1 = {0.f,0.f}, mB0 = {0.f,0.f}, mB1 = {0.f,0.f};
  #pragma unroll
  for (int j = 0; j < 2; ++j) {
    float4 bb = b1v[j0 + j];
    v2f aA0 = {bb.x, bb.y}, aA1 = {bb.z, bb.w};
    v2f aB0 = {bb.x, bb.y}, aB1 = {bb.z, bb.w};
    #pragma unroll
    for (int i = 0; i < 4; ++i) {
      float4 wv = W1v[i * 8 + j0 + j];
      aA0 = pkfma(yA[i], wv.x, wv.y, aA0); aA1 = pkfma(yA[i], wv.z, wv.w, aA1);
      aB0 = pkfma(yB[i], wv.x, wv.y, aB0); aB1 = pkfma(yB[i], wv.z, wv.w, aB1);
    }
    SBAR();
    float hA0 = ftanhp(aA0.x), hA1 = ftanhp(aA0.y);
    float hA2 = ftanhp(aA1.x), hA3 = ftanhp(aA1.y);
    float hB0 = ftanhp(aB0.x), hB1 = ftanhp(aB0.y);
    float hB2 = ftanhp(aB1.x), hB3 = ftanhp(aB1.y);
    float4 w0 = W2v[(4*j + 0) * 4 + p];
    mA0 = pkfma(hA0, w0.x, w0.y, mA0); mA1 = pkfma(hA0, w0.z, w0.w, mA1);
    mB0 = pkfma(hB0, w0.x, w0.y, mB0); mB1 = pkfma(hB0, w0.z, w0.w, mB1);
    float4 w1 = W2v[(4*j + 1) * 4 + p];
    mA0 = pkfma(hA1, w1.x, w1.y, mA0); mA1 = pkfma(hA1, w1.z, w1.w, mA1);
    mB0 = pkfma(hB1, w1.x, w1.y, mB0); mB1 = pkfma(hB1, w1.z, w1.w, mB1);
    float4 w2 = W2v[(4*j + 2) * 4 + p];
    mA0 = pkfma(hA2, w2.x, w2.y, mA0); mA1 = pkfma(hA2, w2.z, w2.w, mA1);
    mB0 = pkfma(hB2, w2.x, w2.y, mB0); mB1 = pkfma(hB2, w2.z, w2.w, mB1);
    float4 w3 = W2v[(4*j + 3) * 4 + p];
    mA0 = pkfma(hA3, w3.x, w3.y, mA0); mA1 = pkfma(hA3, w3.z, w3.w, mA1);
    mB0 = pkfma(hB3, w3.x, w3.y, mB0); mB1 = pkfma(hB3, w3.z, w3.w, mB1);
    SBAR();
  }

  // ---- gating layer 1 ----
  float tmA[8], tmB[8];
  #pragma unroll
  for (int j = 0; j < 2; ++j) {
    float4 bb = gb1v[j0 + j];
    v2f aA0 = {bb.x, bb.y}, aA1 = {bb.z, bb.w};
    v2f aB0 = {bb.x, bb.y}, aB1 = {bb.z, bb.w};
    #pragma unroll
    for (int i = 0; i < 4; ++i) {
      float4 wv = G1v[i * 8 + j0 + j];
      aA0 = pkfma(yA[i], wv.x, wv.y, aA0); aA1 = pkfma(yA[i], wv.z, wv.w, aA1);
      aB0 = pkfma(yB[i], wv.x, wv.y, aB0); aB1 = pkfma(yB[i], wv.z, wv.w, aB1);
    }
    tmA[4*j+0] = ftanhp(aA0.x); tmA[4*j+1] = ftanhp(aA0.y);
    tmA[4*j+2] = ftanhp(aA1.x); tmA[4*j+3] = ftanhp(aA1.y);
    tmB[4*j+0] = ftanhp(aB0.x); tmB[4*j+1] = ftanhp(aB0.y);
    tmB[4*j+2] = ftanhp(aB1.x); tmB[4*j+3] = ftanhp(aB1.y);
    SBAR();
  }
  lnz8_quad(tmA);
  lnz8_quad(tmB);

  // ---- gating layer 2: weight reads shared by both systems ----
  float umA[8], umB[8];
  {
    float4 bb0 = gb2v[j0], bb1 = gb2v[j0 + 1];
    v2f aA00 = {bb0.x, bb0.y}, aA01 = {bb0.z, bb0.w};
    v2f aA10 = {bb1.x, bb1.y}, aA11 = {bb1.z, bb1.w};
    v2f aB00 = {bb0.x, bb0.y}, aB01 = {bb0.z, bb0.w};
    v2f aB10 = {bb1.x, bb1.y}, aB11 = {bb1.z, bb1.w};

#define G2_GROUP(RQ, GA, GB)                                            \
    _Pragma("unroll")                                                   \
    for (int i = 0; i < 8; ++i) {                                       \
      float sA = (GA); float sB = (GB);                                 \
      float4 w0 = G2v[((RQ) + i) * 8 + j0];                             \
      aA00 = pkfma(sA, w0.x, w0.y, aA00); aA01 = pkfma(sA, w0.z, w0.w, aA01); \
      aB00 = pkfma(sB, w0.x, w0.y, aB00); aB01 = pkfma(sB, w0.z, w0.w, aB01); \
      float4 w1 = G2v[((RQ) + i) * 8 + j0 + 1];                         \
      aA10 = pkfma(sA, w1.x, w1.y, aA10); aA11 = pkfma(sA, w1.z, w1.w, aA11); \
      aB10 = pkfma(sB, w1.x, w1.y, aB10); aB11 = pkfma(sB, w1.z, w1.w, aB11); \
      if (i == 3) SBAR();                                               \
    }                                                                   \
    SBAR();

    G2_GROUP(r0,        tmA[i],        tmB[i])
    G2_GROUP(r0 ^ 8,    XOR1(tmA[i]),  XOR1(tmB[i]))
    G2_GROUP(r0 ^ 16,   XOR2(tmA[i]),  XOR2(tmB[i]))
    G2_GROUP(r0 ^ 24,   XOR3(tmA[i]),  XOR3(tmB[i]))
#undef G2_GROUP

    umA[0] = ftanhp(aA00.x); umA[1] = ftanhp(aA00.y);
    umA[2] = ftanhp(aA01.x); umA[3] = ftanhp(aA01.y);
    umA[4] = ftanhp(aA10.x); umA[5] = ftanhp(aA10.y);
    umA[6] = ftanhp(aA11.x); umA[7] = ftanhp(aA11.y);
    umB[0] = ftanhp(aB00.x); umB[1] = ftanhp(aB00.y);
    umB[2] = ftanhp(aB01.x); umB[3] = ftanhp(aB01.y);
    umB[4] = ftanhp(aB10.x); umB[5] = ftanhp(aB10.y);
    umB[6] = ftanhp(aB11.x); umB[7] = ftanhp(aB11.y);
  }
  lnz8_quad(umA);
  lnz8_quad(umB);

  // ---- G3' partials over my 8 rows, then quad-reduce (DPP) ----
  v2f zA0 = {0.f,0.f}, zA1 = {0.f,0.f}, zB0 = {0.f,0.f}, zB1 = {0.f,0.f};
  #pragma unroll
  for (int i = 0; i < 8; ++i) {
    float4 wv = G3v[i * 4 + p];   // remapped slot for row 8p+i
    zA0 = pkfma(umA[i], wv.x, wv.y, zA0); zA1 = pkfma(umA[i], wv.z, wv.w, zA1);
    zB0 = pkfma(umB[i], wv.x, wv.y, zB0); zB1 = pkfma(umB[i], wv.z, wv.w, zB1);
    if (i == 3) SBAR();
  }
  SBAR();

  const float NL2E = -1.4426950408889634f;  // -log2(e)
  float4 b2v  = *(const float4*)w->b2;
  float4 gb3v = *(const float4*)w->gb3;
  {
    float zx = zA0.x, zy = zA0.y, zz = zA1.x, zw = zA1.y;
    float mx = mA0.x, my = mA0.y, mz = mA1.x, mw = mA1.y;
    zx += XOR1(zx); zx += XOR2(zx);
    zy += XOR1(zy); zy += XOR2(zy);
    zz += XOR1(zz); zz += XOR2(zz);
    zw += XOR1(zw); zw += XOR2(zw);
    mx += XOR1(mx); mx += XOR2(mx);
    my += XOR1(my); my += XOR2(my);
    mz += XOR1(mz); mz += XOR2(mz);
    mw += XOR1(mw); mw += XOR2(mw);
    zx += gb3v.x; zy += gb3v.y; zz += gb3v.z; zw += gb3v.w;
    outA[0] = (mx + b2v.x) * __builtin_amdgcn_exp2f(NL2E * zx * zx);
    outA[1] = (my + b2v.y) * __builtin_amdgcn_exp2f(NL2E * zy * zy);
    outA[2] = (mz + b2v.z) * __builtin_amdgcn_exp2f(NL2E * zz * zz);
    outA[3] = (mw + b2v.w) * __builtin_amdgcn_exp2f(NL2E * zw * zw);
  }
  {
    float zx = zB0.x, zy = zB0.y, zz = zB1.x, zw = zB1.y;
    float mx = mB0.x, my = mB0.y, mz = mB1.x, mw = mB1.y;
    zx += XOR1(zx); zx += XOR2(zx);
    zy += XOR1(zy); zy += XOR2(zy);
    zz += XOR1(zz); zz += XOR2(zz);
    zw += XOR1(zw); zw += XOR2(zw);
    mx += XOR1(mx); mx += XOR2(mx);
    my += XOR1(my); my += XOR2(my);
    mz += XOR1(mz); mz += XOR2(mz);
    mw += XOR1(mw); mw += XOR2(mw);
    zx += gb3v.x; zy += gb3v.y; zz += gb3v.z; zw += gb3v.w;
    outB[0] = (mx + b2v.x) * __builtin_amdgcn_exp2f(NL2E * zx * zx);
    outB[1] = (my + b2v.y) * __builtin_amdgcn_exp2f(NL2E * zy * zy);
    outB[2] = (mz + b2v.z) * __builtin_amdgcn_exp2f(NL2E * zz * zz);
    outB[3] = (mw + b2v.w) * __builtin_amdgcn_exp2f(NL2E * zw * zw);
  }
}

// (256,1): the ONLY config observed to allocate >128 VGPRs without spilling
// (R4: 212 VGPR, FETCH ~1 MB). waves_per_eu(2,2) squeezed to 128 + spill (R14).
__global__ __launch_bounds__(256, 1) void ode_kernel(
    const float* __restrict__ s_grid, const float* __restrict__ y0,
    const float* __restrict__ W1, const float* __restrict__ b1,
    const float* __restrict__ W2, const float* __restrict__ b2,
    const float* __restrict__ G1, const float* __restrict__ gb1,
    const float* __restrict__ l1g, const float* __restrict__ l1b,
    const float* __restrict__ G2, const float* __restrict__ gb2,
    const float* __restrict__ l2g, const float* __restrict__ l2b,
    const float* __restrict__ G3, const float* __restrict__ gb3,
    float* __restrict__ out, int T, int B) {
  __shared__ WS w;
  __shared__ float sg[512];
  const int tx = threadIdx.x;
  const float TL2E = 2.8853900817779268f;   // 2*log2(e)

  for (int i = tx; i < 128; i += 256) {
    w.W1[i] = W1[i] * TL2E;
    w.G1[i] = G1[i] * TL2E;
  }
  for (int i = tx; i < 1024; i += 256) w.G2[i] = G2[i] * l1g[i >> 5] * TL2E;
  if (tx < 32) {
    const int d = (tx & 7) * 4 + (tx >> 3);   // row remap
    ((float4*)w.W2)[d] = ((const float4*)W2)[tx];
    float4 g3 = ((const float4*)G3)[tx];
    const float s3 = l2g[tx];
    g3.x *= s3; g3.y *= s3; g3.z *= s3; g3.w *= s3;
    ((float4*)w.G3)[d] = g3;
    w.b1[tx]  = b1[tx]  * TL2E;
    w.gb1[tx] = gb1[tx] * TL2E;
    float acc = gb2[tx];
    for (int r = 0; r < 32; ++r) acc = fmaf(l1b[r], G2[r * 32 + tx], acc);
    w.gb2[tx] = acc * TL2E;
  }
  if (tx < 4) {
    w.b2[tx] = b2[tx];
    float acc = gb3[tx];
    for (int r = 0; r < 32; ++r) acc = fmaf(l2b[r], G3[r * 4 + tx], acc);
    w.gb3[tx] = acc;
  }
  for (int i = tx; i < T && i < 512; i += 256) sg[i] = s_grid[i];
  __syncthreads();

  const int tid  = blockIdx.x * 256 + tx;
  const int quad = tid >> 2;       // one quad serves TWO systems
  const int p    = tid & 3;
  const int sA   = 2 * quad;
  if (sA + 1 >= B + 1) return;     // B even

  float4 yA0 = ((const float4*)y0)[sA];
  float4 yB0 = ((const float4*)y0)[sA + 1];
  float yA[4] = {yA0.x, yA0.y, yA0.z, yA0.w};
  float yB[4] = {yB0.x, yB0.y, yB0.z, yB0.w};

  // lane p stores component p of each system; flat idx = t*4B + 8*quad + p (+4)
  {
    const size_t base = (size_t)8 * quad + p;
    float a = (p == 0) ? yA[0] : ((p == 1) ? yA[1] : ((p == 2) ? yA[2] : yA[3]));
    float b = (p == 0) ? yB[0] : ((p == 1) ? yB[1] : ((p == 2) ? yB[2] : yB[3]));
    out[base] = a;
    out[base + 4] = b;
  }

  #pragma unroll 1
  for (int t = 0; t < T - 1; ++t) {
    const float h = sg[t + 1] - sg[t];
    float kA[4], kB[4], ksA[4], ksB[4], ytA[4], ytB[4];

    fode4x2(&w, p, yA, yB, kA, kB);
    #pragma unroll
    for (int c = 0; c < 4; ++c) {
      ksA[c] = kA[c]; ytA[c] = fmaf(0.5f * h, kA[c], yA[c]);
      ksB[c] = kB[c]; ytB[c] = fmaf(0.5f * h, kB[c], yB[c]);
    }
    SBAR();
    fode4x2(&w, p, ytA, ytB, kA, kB);
    #pragma unroll
    for (int c = 0; c < 4; ++c) {
      ksA[c] = fmaf(2.0f, kA[c], ksA[c]); ytA[c] = fmaf(0.5f * h, kA[c], yA[c]);
      ksB[c] = fmaf(2.0f, kB[c], ksB[c]); ytB[c] = fmaf(0.5f * h, kB[c], yB[c]);
    }
    SBAR();
    fode4x2(&w, p, ytA, ytB, kA, kB);
    #pragma unroll
    for (int c = 0; c < 4; ++c) {
      ksA[c] = fmaf(2.0f, kA[c], ksA[c]); ytA[c] = fmaf(h, kA[c], yA[c]);
      ksB[c] = fmaf(2.0f, kB[c], ksB[c]); ytB[c] = fmaf(h, kB[c], yB[c]);
    }
    SBAR();
    fode4x2(&w, p, ytA, ytB, kA, kB);
    #pragma unroll
    for (int c = 0; c < 4; ++c) {
      yA[c] = fmaf(h * (1.0f / 6.0f), ksA[c] + kA[c], yA[c]);
      yB[c] = fmaf(h * (1.0f / 6.0f), ksB[c] + kB[c], yB[c]);
    }

    const size_t base = (size_t)(t + 1) * 4 * B + (size_t)8 * quad + p;
    float a = (p == 0) ? yA[0] : ((p == 1) ? yA[1] : ((p == 2) ? yA[2] : yA[3]));
    float b = (p == 0) ? yB[0] : ((p == 1) ? yB[1] : ((p == 2) ? yB[2] : yB[3]));
    out[base] = a;
    out[base + 4] = b;
  }
}

extern "C" void kernel_launch(void* const* d_in, const int* in_sizes, int n_in,
                              void* d_out, int out_size, void* d_ws, size_t ws_size,
                              hipStream_t stream) {
  const float* s_grid = (const float*)d_in[0];
  const float* y0     = (const float*)d_in[1];
  const float* W1     = (const float*)d_in[2];
  const float* b1     = (const float*)d_in[3];
  const float* W2     = (const float*)d_in[4];
  const float* b2     = (const float*)d_in[5];
  const float* G1     = (const float*)d_in[6];
  const float* gb1    = (const float*)d_in[7];
  const float* l1g    = (const float*)d_in[8];
  const float* l1b    = (const float*)d_in[9];
  const float* G2     = (const float*)d_in[10];
  const float* gb2    = (const float*)d_in[11];
  const float* l2g    = (const float*)d_in[12];
  const float* l2b    = (const float*)d_in[13];
  const float* G3     = (const float*)d_in[14];
  const float* gb3    = (const float*)d_in[15];

  const int T = in_sizes[0];
  const int B = in_sizes[1] / 4;

  const long long threads = 2LL * B;   // 4 lanes per 2 systems
  dim3 block(256);
  dim3 grid((unsigned)((threads + 255) / 256));
  hipLaunchKernelGGL(ode_kernel, grid, block, 0, stream,
                     s_grid, y0, W1, b1, W2, b2, G1, gb1, l1g, l1b,
                     G2, gb2, l2g, l2b, G3, gb3, (float*)d_out, T, B);
}

// Round 16
// 4008.575 us; speedup vs baseline: 16.2322x; 11.5063x over previous
//
#include <hip/hip_runtime.h>
#include <math.h>

typedef float v2f __attribute__((ext_vector_type(2)));
typedef _Float16 half2v __attribute__((ext_vector_type(2)));

#define EPSV 1e-5f
#define SBAR() __builtin_amdgcn_sched_barrier(0)

// Cross-lane within a 4-lane quad via DPP quad_perm (pure VALU, 1 cyc).
template <int CTRL>
__device__ __forceinline__ float qp(float x) {
  return __int_as_float(
      __builtin_amdgcn_update_dpp(0, __float_as_int(x), CTRL, 0xF, 0xF, true));
}
template <int CTRL>
__device__ __forceinline__ unsigned qpu(unsigned x) {
  return (unsigned)__builtin_amdgcn_update_dpp(0, (int)x, CTRL, 0xF, 0xF, true);
}
#define XOR1(x) qp<0xB1>(x)   // quad_perm [1,0,3,2]
#define XOR2(x) qp<0x4E>(x)   // quad_perm [2,3,0,1]
#define XOR3(x) qp<0x1B>(x)   // quad_perm [3,2,1,0]
#define XOR1U(x) qpu<0xB1>(x)
#define XOR2U(x) qpu<0x4E>(x)
#define XOR3U(x) qpu<0x1B>(x)

// R16: G2 stored as f16 ROW-PAIRS (u32 = rows {2rp,2rp+1} of one col,
// pre-scaled by l1g*2log2e). One b128 read = 8 f16 weights = 16 MACs via
// v_dot2_f32_f16 -> G2 LDS reads halve (64->32/lane-eval), VALU count same.
// W2/G3 row-remapped (r&7)*4+(r>>3): quad conflict-free. LN affines folded.
struct __align__(16) WS {
  float W1[128]; float b1[32]; float W2[128]; float b2[4];
  float G1[128]; float gb1[32];
  unsigned G2h[512]; float gb2[32];
  float G3[128]; float gb3[4];
};

// packed a += s * {wx,wy} -> v_pk_fma_f32. v2f ONLY as named locals (R6 lesson).
__device__ __forceinline__ v2f pkfma(float s, float wx, float wy, v2f a) {
  v2f w = {wx, wy};
  v2f sv = {s, s};
  return __builtin_elementwise_fma(sv, w, a);
}

// f32 += dot(f16pair(w), f16pair(t)) -- v_dot2_f32_f16; fallback unpacks.
__device__ __forceinline__ float fdot2u(unsigned wbits, unsigned tbits, float acc) {
#if __has_builtin(__builtin_amdgcn_fdot2)
  return __builtin_amdgcn_fdot2(__builtin_bit_cast(half2v, wbits),
                                __builtin_bit_cast(half2v, tbits), acc, false);
#else
  half2v wv = __builtin_bit_cast(half2v, wbits);
  half2v tv = __builtin_bit_cast(half2v, tbits);
  acc = fmaf((float)wv.x, (float)tv.x, acc);
  return fmaf((float)wv.y, (float)tv.y, acc);
#endif
}

__device__ __forceinline__ unsigned pkf16(float lo, float hi) {
  return __builtin_bit_cast(unsigned, __builtin_amdgcn_cvt_pkrtz(lo, hi));
}

// tanh from PRE-SCALED arg a = 2*log2(e)*x: tanh(x)=1-2/(exp2(a)+1).
__device__ __forceinline__ float ftanhp(float a) {
  float e = __builtin_amdgcn_exp2f(a);
  float r = __builtin_amdgcn_rcpf(e + 1.0f);
  return fmaf(-2.0f, r, 1.0f);
}

// Pure normalize over 32 values held 8-per-lane across a quad (DPP reduce).
__device__ __forceinline__ void lnz8_quad(float* t) {
  float s = 0.f, ss = 0.f;
  #pragma unroll
  for (int i = 0; i < 8; ++i) { s += t[i]; ss = fmaf(t[i], t[i], ss); }
  s += XOR1(s);  ss += XOR1(ss);
  s += XOR2(s);  ss += XOR2(ss);
  float m = s * 0.03125f;
  float v = fmaf(-m, m, ss * 0.03125f);
  float r = __frsqrt_rn(v + EPSV);
  float nmr = -m * r;
  #pragma unroll
  for (int i = 0; i < 8; ++i) t[i] = fmaf(t[i], r, nmr);
}

// f-eval split across a 4-lane quad: lane p owns cols [8p, 8p+8).
__device__ __forceinline__ void fode4(const WS* w, int p, const float y[4],
                                      float out[4]) {
  const float4* W1v  = (const float4*)w->W1;
  const float4* b1v  = (const float4*)w->b1;
  const float4* W2v  = (const float4*)w->W2;   // row-remapped
  const float4* G1v  = (const float4*)w->G1;
  const float4* gb1v = (const float4*)w->gb1;
  const uint4*  G2p  = (const uint4*)w->G2h;   // f16 rowpair-major [16][32]
  const float4* gb2v = (const float4*)w->gb2;
  const float4* G3v  = (const float4*)w->G3;   // row-remapped, l2g-scaled
  const int j0 = 2 * p;   // my float4 col-group base (of 8)
  const int rp0 = 4 * p;  // my rowpair base (of 16)

  // ---- magnitude net: partial over my 8 hidden units ----
  v2f m0 = {0.f, 0.f}, m1 = {0.f, 0.f};
  #pragma unroll
  for (int j = 0; j < 2; ++j) {
    float4 bb = b1v[j0 + j];
    v2f a0 = {bb.x, bb.y}, a1 = {bb.z, bb.w};
    #pragma unroll
    for (int i = 0; i < 4; ++i) {
      float4 wv = W1v[i * 8 + j0 + j];
      a0 = pkfma(y[i], wv.x, wv.y, a0);
      a1 = pkfma(y[i], wv.z, wv.w, a1);
    }
    SBAR();   // close W1-load window before W2 loads open
    float h0 = ftanhp(a0.x), h1 = ftanhp(a0.y), h2 = ftanhp(a1.x), h3 = ftanhp(a1.y);
    float4 w0 = W2v[(4*j + 0) * 4 + p];
    m0 = pkfma(h0, w0.x, w0.y, m0); m1 = pkfma(h0, w0.z, w0.w, m1);
    float4 w1 = W2v[(4*j + 1) * 4 + p];
    m0 = pkfma(h1, w1.x, w1.y, m0); m1 = pkfma(h1, w1.z, w1.w, m1);
    float4 w2 = W2v[(4*j + 2) * 4 + p];
    m0 = pkfma(h2, w2.x, w2.y, m0); m1 = pkfma(h2, w2.z, w2.w, m1);
    float4 w3 = W2v[(4*j + 3) * 4 + p];
    m0 = pkfma(h3, w3.x, w3.y, m0); m1 = pkfma(h3, w3.z, w3.w, m1);
    SBAR();
  }

  // ---- gating layer 1: my 8 of t = normalize(tanh(y@G1+gb1)) ----
  float tm[8];
  #pragma unroll
  for (int j = 0; j < 2; ++j) {
    float4 bb = gb1v[j0 + j];
    v2f a0 = {bb.x, bb.y}, a1 = {bb.z, bb.w};
    #pragma unroll
    for (int i = 0; i < 4; ++i) {
      float4 wv = G1v[i * 8 + j0 + j];
      a0 = pkfma(y[i], wv.x, wv.y, a0);
      a1 = pkfma(y[i], wv.z, wv.w, a1);
    }
    tm[4*j+0] = ftanhp(a0.x); tm[4*j+1] = ftanhp(a0.y);
    tm[4*j+2] = ftanhp(a1.x); tm[4*j+3] = ftanhp(a1.y);
    SBAR();
  }
  lnz8_quad(tm);

  // ---- gating layer 2 via f16 dot2: my 8 cols of u ----
  float um[8];
  {
    // pack my t row-pairs to f16 (rows 8p+2i, 8p+2i+1)
    unsigned tp0 = pkf16(tm[0], tm[1]);
    unsigned tp1 = pkf16(tm[2], tm[3]);
    unsigned tp2 = pkf16(tm[4], tm[5]);
    unsigned tp3 = pkf16(tm[6], tm[7]);

    float4 bb0 = gb2v[j0], bb1 = gb2v[j0 + 1];
    float c0 = bb0.x, c1 = bb0.y, c2 = bb0.z, c3 = bb0.w;
    float c4 = bb1.x, c5 = bb1.y, c6 = bb1.z, c7 = bb1.w;

    // per rowpair: 2 uint4 reads (my 8 cols), 8 dot2 (16 MACs)
#define G2RP(RP, TQ)                                                  \
    {                                                                 \
      unsigned tq = (TQ);                                             \
      uint4 wa = G2p[(RP) * 8 + 2 * p];                               \
      uint4 wb = G2p[(RP) * 8 + 2 * p + 1];                           \
      c0 = fdot2u(wa.x, tq, c0); c1 = fdot2u(wa.y, tq, c1);           \
      c2 = fdot2u(wa.z, tq, c2); c3 = fdot2u(wa.w, tq, c3);           \
      c4 = fdot2u(wb.x, tq, c4); c5 = fdot2u(wb.y, tq, c5);           \
      c6 = fdot2u(wb.z, tq, c6); c7 = fdot2u(wb.w, tq, c7);           \
    }
#define G2GRP(RPB, E0, E1, E2, E3)                                    \
    G2RP((RPB) + 0, E0) G2RP((RPB) + 1, E1)                           \
    SBAR();                                                           \
    G2RP((RPB) + 2, E2) G2RP((RPB) + 3, E3)                           \
    SBAR();

    G2GRP(rp0,       tp0,        tp1,        tp2,        tp3)
    G2GRP(rp0 ^ 4,   XOR1U(tp0), XOR1U(tp1), XOR1U(tp2), XOR1U(tp3))
    G2GRP(rp0 ^ 8,   XOR2U(tp0), XOR2U(tp1), XOR2U(tp2), XOR2U(tp3))
    G2GRP(rp0 ^ 12,  XOR3U(tp0), XOR3U(tp1), XOR3U(tp2), XOR3U(tp3))
#undef G2GRP
#undef G2RP

    um[0] = ftanhp(c0); um[1] = ftanhp(c1);
    um[2] = ftanhp(c2); um[3] = ftanhp(c3);
    um[4] = ftanhp(c4); um[5] = ftanhp(c5);
    um[6] = ftanhp(c6); um[7] = ftanhp(c7);
  }
  lnz8_quad(um);

  // ---- G3' partial over my 8 rows, then quad-reduce (DPP) ----
  v2f z0 = {0.f, 0.f}, z1 = {0.f, 0.f};
  #pragma unroll
  for (int i = 0; i < 8; ++i) {
    float4 wv = G3v[i * 4 + p];   // remapped slot for row 8p+i
    z0 = pkfma(um[i], wv.x, wv.y, z0);
    z1 = pkfma(um[i], wv.z, wv.w, z1);
    if (i == 3) SBAR();
  }
  SBAR();

  const float NL2E = -1.4426950408889634f;  // -log2(e)
  float4 b2v  = *(const float4*)w->b2;
  float4 gb3v = *(const float4*)w->gb3;
  float zx = z0.x, zy = z0.y, zz = z1.x, zw = z1.y;
  float mx = m0.x, my = m0.y, mz = m1.x, mw = m1.y;
  zx += XOR1(zx); zx += XOR2(zx);
  zy += XOR1(zy); zy += XOR2(zy);
  zz += XOR1(zz); zz += XOR2(zz);
  zw += XOR1(zw); zw += XOR2(zw);
  mx += XOR1(mx); mx += XOR2(mx);
  my += XOR1(my); my += XOR2(my);
  mz += XOR1(mz); mz += XOR2(mz);
  mw += XOR1(mw); mw += XOR2(mw);
  zx += gb3v.x; zy += gb3v.y; zz += gb3v.z; zw += gb3v.w;
  out[0] = (mx + b2v.x) * __builtin_amdgcn_exp2f(NL2E * zx * zx);
  out[1] = (my + b2v.y) * __builtin_amdgcn_exp2f(NL2E * zy * zy);
  out[2] = (mz + b2v.z) * __builtin_amdgcn_exp2f(NL2E * zz * zz);
  out[3] = (mw + b2v.w) * __builtin_amdgcn_exp2f(NL2E * zw * zw);
}

__global__ __launch_bounds__(256, 2) void ode_kernel(
    const float* __restrict__ s_grid, const float* __restrict__ y0,
    const float* __restrict__ W1, const float* __restrict__ b1,
    const float* __restrict__ W2, const float* __restrict__ b2,
    const float* __restrict__ G1, const float* __restrict__ gb1,
    const float* __restrict__ l1g, const float* __restrict__ l1b,
    const float* __restrict__ G2, const float* __restrict__ gb2,
    const float* __restrict__ l2g, const float* __restrict__ l2b,
    const float* __restrict__ G3, const float* __restrict__ gb3,
    float* __restrict__ out, int T, int B) {
  __shared__ WS w;
  __shared__ float sg[512];
  const int tx = threadIdx.x;
  const float TL2E = 2.8853900817779268f;   // 2*log2(e)

  for (int i = tx; i < 128; i += 256) {
    w.W1[i] = W1[i] * TL2E;
    w.G1[i] = G1[i] * TL2E;
  }
  // G2h: f16 rowpair-pack of G2' = (l1g o rows) * 2log2e
  for (int i = tx; i < 512; i += 256) {
    const int rp = i >> 5, c = i & 31;
    float h0 = G2[(2 * rp) * 32 + c] * l1g[2 * rp] * TL2E;
    float h1 = G2[(2 * rp + 1) * 32 + c] * l1g[2 * rp + 1] * TL2E;
    w.G2h[i] = pkf16(h0, h1);
  }
  if (tx < 32) {
    const int d = (tx & 7) * 4 + (tx >> 3);   // row remap
    ((float4*)w.W2)[d] = ((const float4*)W2)[tx];
    float4 g3 = ((const float4*)G3)[tx];
    const float s3 = l2g[tx];
    g3.x *= s3; g3.y *= s3; g3.z *= s3; g3.w *= s3;
    ((float4*)w.G3)[d] = g3;
    w.b1[tx]  = b1[tx]  * TL2E;
    w.gb1[tx] = gb1[tx] * TL2E;
    float acc = gb2[tx];
    for (int r = 0; r < 32; ++r) acc = fmaf(l1b[r], G2[r * 32 + tx], acc);
    w.gb2[tx] = acc * TL2E;
  }
  if (tx < 4) {
    w.b2[tx] = b2[tx];
    float acc = gb3[tx];
    for (int r = 0; r < 32; ++r) acc = fmaf(l2b[r], G3[r * 4 + tx], acc);
    w.gb3[tx] = acc;
  }
  for (int i = tx; i < T && i < 512; i += 256) sg[i] = s_grid[i];
  __syncthreads();

  const int tid = blockIdx.x * 256 + tx;
  const int sys = tid >> 2;   // one system per 4-lane quad
  const int p   = tid & 3;    // my column/row quarter
  if (sys >= B) return;

  float4 y0v = ((const float4*)y0)[sys];
  float y[4] = {y0v.x, y0v.y, y0v.z, y0v.w};

  // coalesced component store: lane p stores component p at flat idx t*4B+tid
  {
    float yv = (p == 0) ? y[0] : ((p == 1) ? y[1] : ((p == 2) ? y[2] : y[3]));
    out[tid] = yv;
  }

  #pragma unroll 1
  for (int t = 0; t < T - 1; ++t) {
    const float h = sg[t + 1] - sg[t];
    float k[4], ksum[4], yt[4];

    fode4(&w, p, y, k);
    #pragma unroll
    for (int c = 0; c < 4; ++c) { ksum[c] = k[c]; yt[c] = fmaf(0.5f * h, k[c], y[c]); }
    SBAR();
    fode4(&w, p, yt, k);
    #pragma unroll
    for (int c = 0; c < 4; ++c) { ksum[c] = fmaf(2.0f, k[c], ksum[c]); yt[c] = fmaf(0.5f * h, k[c], y[c]); }
    SBAR();
    fode4(&w, p, yt, k);
    #pragma unroll
    for (int c = 0; c < 4; ++c) { ksum[c] = fmaf(2.0f, k[c], ksum[c]); yt[c] = fmaf(h, k[c], y[c]); }
    SBAR();
    fode4(&w, p, yt, k);
    #pragma unroll
    for (int c = 0; c < 4; ++c)
      y[c] = fmaf(h * (1.0f / 6.0f), ksum[c] + k[c], y[c]);

    float yv = (p == 0) ? y[0] : ((p == 1) ? y[1] : ((p == 2) ? y[2] : y[3]));
    out[(size_t)(t + 1) * 4 * B + tid] = yv;
  }
}

extern "C" void kernel_launch(void* const* d_in, const int* in_sizes, int n_in,
                              void* d_out, int out_size, void* d_ws, size_t ws_size,
                              hipStream_t stream) {
  const float* s_grid = (const float*)d_in[0];
  const float* y0     = (const float*)d_in[1];
  const float* W1     = (const float*)d_in[2];
  const float* b1     = (const float*)d_in[3];
  const float* W2     = (const float*)d_in[4];
  const float* b2     = (const float*)d_in[5];
  const float* G1     = (const float*)d_in[6];
  const float* gb1    = (const float*)d_in[7];
  const float* l1g    = (const float*)d_in[8];
  const float* l1b    = (const float*)d_in[9];
  const float* G2     = (const float*)d_in[10];
  const float* gb2    = (const float*)d_in[11];
  const float* l2g    = (const float*)d_in[12];
  const float* l2b    = (const float*)d_in[13];
  const float* G3     = (const float*)d_in[14];
  const float* gb3    = (const float*)d_in[15];

  const int T = in_sizes[0];
  const int B = in_sizes[1] / 4;

  const long long threads = 4LL * B;   // 4 lanes per system -> 4 waves/SIMD
  dim3 block(256);
  dim3 grid((unsigned)((threads + 255) / 256));
  hipLaunchKernelGGL(ode_kernel, grid, block, 0, stream,
                     s_grid, y0, W1, b1, W2, b2, G1, gb1, l1g, l1b,
                     G2, gb2, l2g, l2b, G3, gb3, (float*)d_out, T, B);
}

// Round 17
// 3825.714 us; speedup vs baseline: 17.0081x; 1.0478x over previous
//
#include <hip/hip_runtime.h>
#include <math.h>

typedef float v2f __attribute__((ext_vector_type(2)));
typedef _Float16 half2v __attribute__((ext_vector_type(2)));

#define EPSV 1e-5f
#define SBAR() __builtin_amdgcn_sched_barrier(0)

// Cross-lane within a 4-lane quad via DPP quad_perm (pure VALU, 1 cyc).
template <int CTRL>
__device__ __forceinline__ float qp(float x) {
  return __int_as_float(
      __builtin_amdgcn_update_dpp(0, __float_as_int(x), CTRL, 0xF, 0xF, true));
}
template <int CTRL>
__device__ __forceinline__ unsigned qpu(unsigned x) {
  return (unsigned)__builtin_amdgcn_update_dpp(0, (int)x, CTRL, 0xF, 0xF, true);
}
#define XOR1(x) qp<0xB1>(x)   // quad_perm [1,0,3,2]
#define XOR2(x) qp<0x4E>(x)   // quad_perm [2,3,0,1]
#define XOR3(x) qp<0x1B>(x)   // quad_perm [3,2,1,0]
#define XOR1U(x) qpu<0xB1>(x)
#define XOR2U(x) qpu<0x4E>(x)
#define XOR3U(x) qpu<0x1B>(x)

// R17: ALL weight tables f16 row/col-pair packed (RTN staging), consumed via
// v_dot2_f32_f16 with packed f16 operands (y, h, t, u). Per-lane LDS reads
// 69 -> ~56; W2/G3 pkfma -> dot2 halves their instr count; scalar accums.
// W1h/G1h: [32 cols][2 u32] (input pairs). W2h/G3h: [16 rowpair-slots][4 cols]
// u32, slot = (rp&3)*4+(rp>>2) (involutive digit swap -> quad conflict-free).
// G2h: [16 rowpairs][32 cols] u32. LN affines + 2log2(e) tanh-arg folds staged.
struct __align__(16) WS {
  unsigned W1h[64]; float b1[32]; unsigned W2h[64]; float b2[4];
  unsigned G1h[64]; float gb1[32];
  unsigned G2h[512]; float gb2[32];
  unsigned G3h[64]; float gb3[4];
};

// f32 += dot(f16pair(w), f16pair(t)) -- v_dot2_f32_f16.
__device__ __forceinline__ float fdot2u(unsigned wbits, unsigned tbits, float acc) {
#if __has_builtin(__builtin_amdgcn_fdot2)
  return __builtin_amdgcn_fdot2(__builtin_bit_cast(half2v, wbits),
                                __builtin_bit_cast(half2v, tbits), acc, false);
#else
  half2v wv = __builtin_bit_cast(half2v, wbits);
  half2v tv = __builtin_bit_cast(half2v, tbits);
  acc = fmaf((float)wv.x, (float)tv.x, acc);
  return fmaf((float)wv.y, (float)tv.y, acc);
#endif
}

__device__ __forceinline__ unsigned pkrtz(float lo, float hi) {
  return __builtin_bit_cast(unsigned, __builtin_amdgcn_cvt_pkrtz(lo, hi));
}
// round-to-nearest pack (staging only)
__device__ __forceinline__ unsigned pkrn(float lo, float hi) {
  half2v h;
  h.x = (_Float16)lo;
  h.y = (_Float16)hi;
  return __builtin_bit_cast(unsigned, h);
}

// tanh from PRE-SCALED arg a = 2*log2(e)*x: tanh(x)=1-2/(exp2(a)+1).
__device__ __forceinline__ float ftanhp(float a) {
  float e = __builtin_amdgcn_exp2f(a);
  float r = __builtin_amdgcn_rcpf(e + 1.0f);
  return fmaf(-2.0f, r, 1.0f);
}

// Pure normalize over 32 values held 8-per-lane across a quad (DPP reduce).
__device__ __forceinline__ void lnz8_quad(float* t) {
  float s = 0.f, ss = 0.f;
  #pragma unroll
  for (int i = 0; i < 8; ++i) { s += t[i]; ss = fmaf(t[i], t[i], ss); }
  s += XOR1(s);  ss += XOR1(ss);
  s += XOR2(s);  ss += XOR2(ss);
  float m = s * 0.03125f;
  float v = fmaf(-m, m, ss * 0.03125f);
  float r = __frsqrt_rn(v + EPSV);
  float nmr = -m * r;
  #pragma unroll
  for (int i = 0; i < 8; ++i) t[i] = fmaf(t[i], r, nmr);
}

// f-eval split across a 4-lane quad: lane p owns cols/rows [8p, 8p+8).
__device__ __forceinline__ void fode4(const WS* w, int p, const float y[4],
                                      float out[4]) {
  const uint4*  W1p  = (const uint4*)w->W1h;   // [16]: idx g = cols 2g,2g+1
  const float4* b1v  = (const float4*)w->b1;
  const uint4*  W2p  = (const uint4*)w->W2h;   // [16 slots][4 cols]
  const uint4*  G1p  = (const uint4*)w->G1h;
  const float4* gb1v = (const float4*)w->gb1;
  const uint4*  G2p  = (const uint4*)w->G2h;   // [16 rp][32 c] as uint4[16][8]
  const float4* gb2v = (const float4*)w->gb2;
  const uint4*  G3p  = (const uint4*)w->G3h;
  const int rp0 = 4 * p;   // my rowpair base (of 16)

  const unsigned yp0 = pkrtz(y[0], y[1]);
  const unsigned yp1 = pkrtz(y[2], y[3]);

  // ---- magnitude net: my 8 hidden units via dot2, then W2 via dot2 ----
  float mx, my, mz, mw;
  {
    float4 bb0 = b1v[2 * p], bb1 = b1v[2 * p + 1];
    uint4 wa0 = W1p[4 * p + 0], wa1 = W1p[4 * p + 1];
    uint4 wa2 = W1p[4 * p + 2], wa3 = W1p[4 * p + 3];
    float a0 = fdot2u(wa0.y, yp1, fdot2u(wa0.x, yp0, bb0.x));
    float a1 = fdot2u(wa0.w, yp1, fdot2u(wa0.z, yp0, bb0.y));
    float a2 = fdot2u(wa1.y, yp1, fdot2u(wa1.x, yp0, bb0.z));
    float a3 = fdot2u(wa1.w, yp1, fdot2u(wa1.z, yp0, bb0.w));
    float a4 = fdot2u(wa2.y, yp1, fdot2u(wa2.x, yp0, bb1.x));
    float a5 = fdot2u(wa2.w, yp1, fdot2u(wa2.z, yp0, bb1.y));
    float a6 = fdot2u(wa3.y, yp1, fdot2u(wa3.x, yp0, bb1.z));
    float a7 = fdot2u(wa3.w, yp1, fdot2u(wa3.z, yp0, bb1.w));
    SBAR();
    unsigned hp0 = pkrtz(ftanhp(a0), ftanhp(a1));
    unsigned hp1 = pkrtz(ftanhp(a2), ftanhp(a3));
    unsigned hp2 = pkrtz(ftanhp(a4), ftanhp(a5));
    unsigned hp3 = pkrtz(ftanhp(a6), ftanhp(a7));
    mx = my = mz = mw = 0.f;
    { uint4 ww = W2p[0 * 4 + p];
      mx = fdot2u(ww.x, hp0, mx); my = fdot2u(ww.y, hp0, my);
      mz = fdot2u(ww.z, hp0, mz); mw = fdot2u(ww.w, hp0, mw); }
    { uint4 ww = W2p[1 * 4 + p];
      mx = fdot2u(ww.x, hp1, mx); my = fdot2u(ww.y, hp1, my);
      mz = fdot2u(ww.z, hp1, mz); mw = fdot2u(ww.w, hp1, mw); }
    { uint4 ww = W2p[2 * 4 + p];
      mx = fdot2u(ww.x, hp2, mx); my = fdot2u(ww.y, hp2, my);
      mz = fdot2u(ww.z, hp2, mz); mw = fdot2u(ww.w, hp2, mw); }
    { uint4 ww = W2p[3 * 4 + p];
      mx = fdot2u(ww.x, hp3, mx); my = fdot2u(ww.y, hp3, my);
      mz = fdot2u(ww.z, hp3, mz); mw = fdot2u(ww.w, hp3, mw); }
    SBAR();
  }

  // ---- gating layer 1: my 8 of t = normalize(tanh(y@G1+gb1)) ----
  float tm[8];
  {
    float4 bb0 = gb1v[2 * p], bb1 = gb1v[2 * p + 1];
    uint4 wa0 = G1p[4 * p + 0], wa1 = G1p[4 * p + 1];
    uint4 wa2 = G1p[4 * p + 2], wa3 = G1p[4 * p + 3];
    tm[0] = ftanhp(fdot2u(wa0.y, yp1, fdot2u(wa0.x, yp0, bb0.x)));
    tm[1] = ftanhp(fdot2u(wa0.w, yp1, fdot2u(wa0.z, yp0, bb0.y)));
    tm[2] = ftanhp(fdot2u(wa1.y, yp1, fdot2u(wa1.x, yp0, bb0.z)));
    tm[3] = ftanhp(fdot2u(wa1.w, yp1, fdot2u(wa1.z, yp0, bb0.w)));
    tm[4] = ftanhp(fdot2u(wa2.y, yp1, fdot2u(wa2.x, yp0, bb1.x)));
    tm[5] = ftanhp(fdot2u(wa2.w, yp1, fdot2u(wa2.z, yp0, bb1.y)));
    tm[6] = ftanhp(fdot2u(wa3.y, yp1, fdot2u(wa3.x, yp0, bb1.z)));
    tm[7] = ftanhp(fdot2u(wa3.w, yp1, fdot2u(wa3.z, yp0, bb1.w)));
    SBAR();
  }
  lnz8_quad(tm);

  // ---- gating layer 2 via f16 dot2: my 8 cols of u ----
  float um[8];
  {
    unsigned tp0 = pkrtz(tm[0], tm[1]);
    unsigned tp1 = pkrtz(tm[2], tm[3]);
    unsigned tp2 = pkrtz(tm[4], tm[5]);
    unsigned tp3 = pkrtz(tm[6], tm[7]);

    float4 bb0 = gb2v[2 * p], bb1 = gb2v[2 * p + 1];
    float c0 = bb0.x, c1 = bb0.y, c2 = bb0.z, c3 = bb0.w;
    float c4 = bb1.x, c5 = bb1.y, c6 = bb1.z, c7 = bb1.w;

#define G2RP(RP, TQ)                                                  \
    {                                                                 \
      unsigned tq = (TQ);                                             \
      uint4 wa = G2p[(RP) * 8 + 2 * p];                               \
      uint4 wb = G2p[(RP) * 8 + 2 * p + 1];                           \
      c0 = fdot2u(wa.x, tq, c0); c1 = fdot2u(wa.y, tq, c1);           \
      c2 = fdot2u(wa.z, tq, c2); c3 = fdot2u(wa.w, tq, c3);           \
      c4 = fdot2u(wb.x, tq, c4); c5 = fdot2u(wb.y, tq, c5);           \
      c6 = fdot2u(wb.z, tq, c6); c7 = fdot2u(wb.w, tq, c7);           \
    }
#define G2GRP(RPB, E0, E1, E2, E3)                                    \
    G2RP((RPB) + 0, E0) G2RP((RPB) + 1, E1)                           \
    G2RP((RPB) + 2, E2) G2RP((RPB) + 3, E3)                           \
    SBAR();

    G2GRP(rp0,       tp0,        tp1,        tp2,        tp3)
    G2GRP(rp0 ^ 4,   XOR1U(tp0), XOR1U(tp1), XOR1U(tp2), XOR1U(tp3))
    G2GRP(rp0 ^ 8,   XOR2U(tp0), XOR2U(tp1), XOR2U(tp2), XOR2U(tp3))
    G2GRP(rp0 ^ 12,  XOR3U(tp0), XOR3U(tp1), XOR3U(tp2), XOR3U(tp3))
#undef G2GRP
#undef G2RP

    um[0] = ftanhp(c0); um[1] = ftanhp(c1);
    um[2] = ftanhp(c2); um[3] = ftanhp(c3);
    um[4] = ftanhp(c4); um[5] = ftanhp(c5);
    um[6] = ftanhp(c6); um[7] = ftanhp(c7);
  }
  lnz8_quad(um);

  // ---- G3' via dot2 over my 4 rowpairs, then quad-reduce (DPP) ----
  float zx, zy, zz, zw;
  {
    unsigned up0 = pkrtz(um[0], um[1]);
    unsigned up1 = pkrtz(um[2], um[3]);
    unsigned up2 = pkrtz(um[4], um[5]);
    unsigned up3 = pkrtz(um[6], um[7]);
    zx = zy = zz = zw = 0.f;
    { uint4 ww = G3p[0 * 4 + p];
      zx = fdot2u(ww.x, up0, zx); zy = fdot2u(ww.y, up0, zy);
      zz = fdot2u(ww.z, up0, zz); zw = fdot2u(ww.w, up0, zw); }
    { uint4 ww = G3p[1 * 4 + p];
      zx = fdot2u(ww.x, up1, zx); zy = fdot2u(ww.y, up1, zy);
      zz = fdot2u(ww.z, up1, zz); zw = fdot2u(ww.w, up1, zw); }
    { uint4 ww = G3p[2 * 4 + p];
      zx = fdot2u(ww.x, up2, zx); zy = fdot2u(ww.y, up2, zy);
      zz = fdot2u(ww.z, up2, zz); zw = fdot2u(ww.w, up2, zw); }
    { uint4 ww = G3p[3 * 4 + p];
      zx = fdot2u(ww.x, up3, zx); zy = fdot2u(ww.y, up3, zy);
      zz = fdot2u(ww.z, up3, zz); zw = fdot2u(ww.w, up3, zw); }
    SBAR();
  }

  const float NL2E = -1.4426950408889634f;  // -log2(e)
  float4 b2v  = *(const float4*)w->b2;
  float4 gb3v = *(const float4*)w->gb3;
  zx += XOR1(zx); zx += XOR2(zx);
  zy += XOR1(zy); zy += XOR2(zy);
  zz += XOR1(zz); zz += XOR2(zz);
  zw += XOR1(zw); zw += XOR2(zw);
  mx += XOR1(mx); mx += XOR2(mx);
  my += XOR1(my); my += XOR2(my);
  mz += XOR1(mz); mz += XOR2(mz);
  mw += XOR1(mw); mw += XOR2(mw);
  zx += gb3v.x; zy += gb3v.y; zz += gb3v.z; zw += gb3v.w;
  out[0] = (mx + b2v.x) * __builtin_amdgcn_exp2f(NL2E * zx * zx);
  out[1] = (my + b2v.y) * __builtin_amdgcn_exp2f(NL2E * zy * zy);
  out[2] = (mz + b2v.z) * __builtin_amdgcn_exp2f(NL2E * zz * zz);
  out[3] = (mw + b2v.w) * __builtin_amdgcn_exp2f(NL2E * zw * zw);
}

__global__ __launch_bounds__(256, 2) void ode_kernel(
    const float* __restrict__ s_grid, const float* __restrict__ y0,
    const float* __restrict__ W1, const float* __restrict__ b1,
    const float* __restrict__ W2, const float* __restrict__ b2,
    const float* __restrict__ G1, const float* __restrict__ gb1,
    const float* __restrict__ l1g, const float* __restrict__ l1b,
    const float* __restrict__ G2, const float* __restrict__ gb2,
    const float* __restrict__ l2g, const float* __restrict__ l2b,
    const float* __restrict__ G3, const float* __restrict__ gb3,
    float* __restrict__ out, int T, int B) {
  __shared__ WS w;
  __shared__ float sg[512];
  const int tx = threadIdx.x;
  const float TL2E = 2.8853900817779268f;   // 2*log2(e)

  // G2h: f16 rowpair-pack of G2' = (l1g o rows) * 2log2e, RTN
  for (int i = tx; i < 512; i += 256) {
    const int rp = i >> 5, c = i & 31;
    w.G2h[i] = pkrn(G2[(2 * rp) * 32 + c] * l1g[2 * rp] * TL2E,
                    G2[(2 * rp + 1) * 32 + c] * l1g[2 * rp + 1] * TL2E);
  }
  if (tx < 64) {
    // W1h/G1h: [32 cols][2 input-pairs]; i = 2c+pair, rows 2*pair, 2*pair+1
    const int c = tx >> 1, pr = tx & 1;
    w.W1h[tx] = pkrn(W1[(2 * pr) * 32 + c] * TL2E,
                     W1[(2 * pr + 1) * 32 + c] * TL2E);
    w.G1h[tx] = pkrn(G1[(2 * pr) * 32 + c] * TL2E,
                     G1[(2 * pr + 1) * 32 + c] * TL2E);
    // W2h/G3h: slot s = i>>2, col = i&3; rp = digit-swap(s)
    const int s = tx >> 2, cc = tx & 3;
    const int rp = (s & 3) * 4 + (s >> 2);
    w.W2h[tx] = pkrn(W2[(2 * rp) * 4 + cc], W2[(2 * rp + 1) * 4 + cc]);
    w.G3h[tx] = pkrn(G3[(2 * rp) * 4 + cc] * l2g[2 * rp],
                     G3[(2 * rp + 1) * 4 + cc] * l2g[2 * rp + 1]);
  }
  if (tx < 32) {
    w.b1[tx]  = b1[tx]  * TL2E;
    w.gb1[tx] = gb1[tx] * TL2E;
    float acc = gb2[tx];                      // LN1 affine fold (bias)
    for (int r = 0; r < 32; ++r) acc = fmaf(l1b[r], G2[r * 32 + tx], acc);
    w.gb2[tx] = acc * TL2E;
  }
  if (tx < 4) {
    w.b2[tx] = b2[tx];
    float acc = gb3[tx];                      // LN2 affine fold (bias)
    for (int r = 0; r < 32; ++r) acc = fmaf(l2b[r], G3[r * 4 + tx], acc);
    w.gb3[tx] = acc;
  }
  for (int i = tx; i < T && i < 512; i += 256) sg[i] = s_grid[i];
  __syncthreads();

  const int tid = blockIdx.x * 256 + tx;
  const int sys = tid >> 2;   // one system per 4-lane quad
  const int p   = tid & 3;    // my column/row quarter
  if (sys >= B) return;

  float4 y0v = ((const float4*)y0)[sys];
  float y[4] = {y0v.x, y0v.y, y0v.z, y0v.w};

  // coalesced component store: lane p stores component p at flat idx t*4B+tid
  {
    float yv = (p == 0) ? y[0] : ((p == 1) ? y[1] : ((p == 2) ? y[2] : y[3]));
    out[tid] = yv;
  }

  #pragma unroll 1
  for (int t = 0; t < T - 1; ++t) {
    const float h = sg[t + 1] - sg[t];
    float k[4], ksum[4], yt[4];

    fode4(&w, p, y, k);
    #pragma unroll
    for (int c = 0; c < 4; ++c) { ksum[c] = k[c]; yt[c] = fmaf(0.5f * h, k[c], y[c]); }
    SBAR();
    fode4(&w, p, yt, k);
    #pragma unroll
    for (int c = 0; c < 4; ++c) { ksum[c] = fmaf(2.0f, k[c], ksum[c]); yt[c] = fmaf(0.5f * h, k[c], y[c]); }
    SBAR();
    fode4(&w, p, yt, k);
    #pragma unroll
    for (int c = 0; c < 4; ++c) { ksum[c] = fmaf(2.0f, k[c], ksum[c]); yt[c] = fmaf(h, k[c], y[c]); }
    SBAR();
    fode4(&w, p, yt, k);
    #pragma unroll
    for (int c = 0; c < 4; ++c)
      y[c] = fmaf(h * (1.0f / 6.0f), ksum[c] + k[c], y[c]);

    float yv = (p == 0) ? y[0] : ((p == 1) ? y[1] : ((p == 2) ? y[2] : y[3]));
    out[(size_t)(t + 1) * 4 * B + tid] = yv;
  }
}

extern "C" void kernel_launch(void* const* d_in, const int* in_sizes, int n_in,
                              void* d_out, int out_size, void* d_ws, size_t ws_size,
                              hipStream_t stream) {
  const float* s_grid = (const float*)d_in[0];
  const float* y0     = (const float*)d_in[1];
  const float* W1     = (const float*)d_in[2];
  const float* b1     = (const float*)d_in[3];
  const float* W2     = (const float*)d_in[4];
  const float* b2     = (const float*)d_in[5];
  const float* G1     = (const float*)d_in[6];
  const float* gb1    = (const float*)d_in[7];
  const float* l1g    = (const float*)d_in[8];
  const float* l1b    = (const float*)d_in[9];
  const float* G2     = (const float*)d_in[10];
  const float* gb2    = (const float*)d_in[11];
  const float* l2g    = (const float*)d_in[12];
  const float* l2b    = (const float*)d_in[13];
  const float* G3     = (const float*)d_in[14];
  const float* gb3    = (const float*)d_in[15];

  const int T = in_sizes[0];
  const int B = in_sizes[1] / 4;

  const long long threads = 4LL * B;   // 4 lanes per system -> 4 waves/SIMD
  dim3 block(256);
  dim3 grid((unsigned)((threads + 255) / 256));
  hipLaunchKernelGGL(ode_kernel, grid, block, 0, stream,
                     s_grid, y0, W1, b1, W2, b2, G1, gb1, l1g, l1b,
                     G2, gb2, l2g, l2b, G3, gb3, (float*)d_out, T, B);
}

// Round 18
// 3676.161 us; speedup vs baseline: 17.7000x; 1.0407x over previous
//
#include <hip/hip_runtime.h>
#include <math.h>

typedef _Float16 half2v __attribute__((ext_vector_type(2)));

#define EPSV 1e-5f
#define SBAR() __builtin_amdgcn_sched_barrier(0)

// Cross-lane within a 4-lane quad via DPP quad_perm (pure VALU, 1 cyc).
template <int CTRL>
__device__ __forceinline__ float qp(float x) {
  return __int_as_float(
      __builtin_amdgcn_update_dpp(0, __float_as_int(x), CTRL, 0xF, 0xF, true));
}
template <int CTRL>
__device__ __forceinline__ unsigned qpu(unsigned x) {
  return (unsigned)__builtin_amdgcn_update_dpp(0, (int)x, CTRL, 0xF, 0xF, true);
}
#define XOR1(x) qp<0xB1>(x)   // quad_perm [1,0,3,2]
#define XOR2(x) qp<0x4E>(x)   // quad_perm [2,3,0,1]
#define XOR3(x) qp<0x1B>(x)   // quad_perm [3,2,1,0]
#define XOR1U(x) qpu<0xB1>(x)
#define XOR2U(x) qpu<0x4E>(x)
#define XOR3U(x) qpu<0x1B>(x)

// R18: r-form tanh (tanh = 1-2r, r = rcp(exp2(a)+1)) -- the -2r+1 fma is
// absorbed into (a) W2h staged as -2*W2 with CS2 colsum init, (b) LN
// normalize constants. All f16 tables as R17; fences relaxed (VGPR budget
// free at 4 waves/SIMD).
struct __align__(16) WS {
  unsigned W1h[64]; float b1[32]; unsigned W2h[64]; float b2[4];
  float CS2[16];    // [p][c]: colsum of W2 rows 8p..8p+7 (f32)
  unsigned G1h[64]; float gb1[32];
  unsigned G2h[512]; float gb2[32];
  unsigned G3h[64]; float gb3[4];
};

// f32 += dot(f16pair(w), f16pair(t)) -- v_dot2_f32_f16.
__device__ __forceinline__ float fdot2u(unsigned wbits, unsigned tbits, float acc) {
#if __has_builtin(__builtin_amdgcn_fdot2)
  return __builtin_amdgcn_fdot2(__builtin_bit_cast(half2v, wbits),
                                __builtin_bit_cast(half2v, tbits), acc, false);
#else
  half2v wv = __builtin_bit_cast(half2v, wbits);
  half2v tv = __builtin_bit_cast(half2v, tbits);
  acc = fmaf((float)wv.x, (float)tv.x, acc);
  return fmaf((float)wv.y, (float)tv.y, acc);
#endif
}

__device__ __forceinline__ unsigned pkrtz(float lo, float hi) {
  return __builtin_bit_cast(unsigned, __builtin_amdgcn_cvt_pkrtz(lo, hi));
}
// round-to-nearest pack (staging only)
__device__ __forceinline__ unsigned pkrn(float lo, float hi) {
  half2v h;
  h.x = (_Float16)lo;
  h.y = (_Float16)hi;
  return __builtin_bit_cast(unsigned, h);
}

// r-form: r = rcp(exp2(a)+1), a pre-scaled by 2*log2(e). tanh(x) = 1 - 2r.
// a->+inf: e->inf, r->0 (tanh 1); a->-inf: e->0, r->1 (tanh -1). Exact.
__device__ __forceinline__ float frf(float a) {
  float e = __builtin_amdgcn_exp2f(a);
  return __builtin_amdgcn_rcpf(e + 1.0f);
}

// LayerNorm normalize over t = 1-2r, 32 values held 8-r-per-lane across a
// quad (DPP reduce). Writes NORMALIZED t back into rv[].
// m_t = 1 - S/16;  E[t^2] = 1 + (SS - S)/8;  var = E[t^2] - m^2
// t_norm = fma(r, -2rr, (1-m)rr)
__device__ __forceinline__ void lnz8r_quad(float* rv) {
  float S = 0.f, SS = 0.f;
  #pragma unroll
  for (int i = 0; i < 8; ++i) { S += rv[i]; SS = fmaf(rv[i], rv[i], SS); }
  S += XOR1(S);  SS += XOR1(SS);
  S += XOR2(S);  SS += XOR2(SS);
  float m   = fmaf(-0.0625f, S, 1.0f);
  float Et2 = fmaf(0.125f, SS - S, 1.0f);
  float v   = fmaf(-m, m, Et2);
  float rr  = __frsqrt_rn(v + EPSV);
  float c1  = -2.0f * rr;
  float c0  = fmaf(-m, rr, rr);
  #pragma unroll
  for (int i = 0; i < 8; ++i) rv[i] = fmaf(rv[i], c1, c0);
}

// f-eval split across a 4-lane quad: lane p owns cols/rows [8p, 8p+8).
__device__ __forceinline__ void fode4(const WS* w, int p, const float y[4],
                                      float out[4]) {
  const uint4*  W1p  = (const uint4*)w->W1h;
  const float4* b1v  = (const float4*)w->b1;
  const uint4*  W2p  = (const uint4*)w->W2h;   // staged -2*W2
  const uint4*  G1p  = (const uint4*)w->G1h;
  const float4* gb1v = (const float4*)w->gb1;
  const uint4*  G2p  = (const uint4*)w->G2h;
  const float4* gb2v = (const float4*)w->gb2;
  const uint4*  G3p  = (const uint4*)w->G3h;
  const int rp0 = 4 * p;

  const unsigned yp0 = pkrtz(y[0], y[1]);
  const unsigned yp1 = pkrtz(y[2], y[3]);

  // ---- magnitude net: h = 1-2r absorbed via -2*W2 + colsum init ----
  float mx, my, mz, mw;
  {
    float4 bb0 = b1v[2 * p], bb1 = b1v[2 * p + 1];
    uint4 wa0 = W1p[4 * p + 0], wa1 = W1p[4 * p + 1];
    uint4 wa2 = W1p[4 * p + 2], wa3 = W1p[4 * p + 3];
    float a0 = fdot2u(wa0.y, yp1, fdot2u(wa0.x, yp0, bb0.x));
    float a1 = fdot2u(wa0.w, yp1, fdot2u(wa0.z, yp0, bb0.y));
    float a2 = fdot2u(wa1.y, yp1, fdot2u(wa1.x, yp0, bb0.z));
    float a3 = fdot2u(wa1.w, yp1, fdot2u(wa1.z, yp0, bb0.w));
    float a4 = fdot2u(wa2.y, yp1, fdot2u(wa2.x, yp0, bb1.x));
    float a5 = fdot2u(wa2.w, yp1, fdot2u(wa2.z, yp0, bb1.y));
    float a6 = fdot2u(wa3.y, yp1, fdot2u(wa3.x, yp0, bb1.z));
    float a7 = fdot2u(wa3.w, yp1, fdot2u(wa3.z, yp0, bb1.w));
    unsigned rp_0 = pkrtz(frf(a0), frf(a1));
    unsigned rp_1 = pkrtz(frf(a2), frf(a3));
    unsigned rp_2 = pkrtz(frf(a4), frf(a5));
    unsigned rp_3 = pkrtz(frf(a6), frf(a7));
    const float4 cs = ((const float4*)w->CS2)[p];
    mx = cs.x; my = cs.y; mz = cs.z; mw = cs.w;
    { uint4 ww = W2p[0 * 4 + p];
      mx = fdot2u(ww.x, rp_0, mx); my = fdot2u(ww.y, rp_0, my);
      mz = fdot2u(ww.z, rp_0, mz); mw = fdot2u(ww.w, rp_0, mw); }
    { uint4 ww = W2p[1 * 4 + p];
      mx = fdot2u(ww.x, rp_1, mx); my = fdot2u(ww.y, rp_1, my);
      mz = fdot2u(ww.z, rp_1, mz); mw = fdot2u(ww.w, rp_1, mw); }
    { uint4 ww = W2p[2 * 4 + p];
      mx = fdot2u(ww.x, rp_2, mx); my = fdot2u(ww.y, rp_2, my);
      mz = fdot2u(ww.z, rp_2, mz); mw = fdot2u(ww.w, rp_2, mw); }
    { uint4 ww = W2p[3 * 4 + p];
      mx = fdot2u(ww.x, rp_3, mx); my = fdot2u(ww.y, rp_3, my);
      mz = fdot2u(ww.z, rp_3, mz); mw = fdot2u(ww.w, rp_3, mw); }
    SBAR();
  }

  // ---- gating layer 1: r-values, then LN-normalize in r-form ----
  float tm[8];
  {
    float4 bb0 = gb1v[2 * p], bb1 = gb1v[2 * p + 1];
    uint4 wa0 = G1p[4 * p + 0], wa1 = G1p[4 * p + 1];
    uint4 wa2 = G1p[4 * p + 2], wa3 = G1p[4 * p + 3];
    tm[0] = frf(fdot2u(wa0.y, yp1, fdot2u(wa0.x, yp0, bb0.x)));
    tm[1] = frf(fdot2u(wa0.w, yp1, fdot2u(wa0.z, yp0, bb0.y)));
    tm[2] = frf(fdot2u(wa1.y, yp1, fdot2u(wa1.x, yp0, bb0.z)));
    tm[3] = frf(fdot2u(wa1.w, yp1, fdot2u(wa1.z, yp0, bb0.w)));
    tm[4] = frf(fdot2u(wa2.y, yp1, fdot2u(wa2.x, yp0, bb1.x)));
    tm[5] = frf(fdot2u(wa2.w, yp1, fdot2u(wa2.z, yp0, bb1.y)));
    tm[6] = frf(fdot2u(wa3.y, yp1, fdot2u(wa3.x, yp0, bb1.z)));
    tm[7] = frf(fdot2u(wa3.w, yp1, fdot2u(wa3.z, yp0, bb1.w)));
  }
  lnz8r_quad(tm);

  // ---- gating layer 2 via f16 dot2: my 8 cols; u kept as r-values ----
  float um[8];
  {
    unsigned tp0 = pkrtz(tm[0], tm[1]);
    unsigned tp1 = pkrtz(tm[2], tm[3]);
    unsigned tp2 = pkrtz(tm[4], tm[5]);
    unsigned tp3 = pkrtz(tm[6], tm[7]);

    float4 bb0 = gb2v[2 * p], bb1 = gb2v[2 * p + 1];
    float c0 = bb0.x, c1 = bb0.y, c2 = bb0.z, c3 = bb0.w;
    float c4 = bb1.x, c5 = bb1.y, c6 = bb1.z, c7 = bb1.w;

#define G2RP(RP, TQ)                                                  \
    {                                                                 \
      unsigned tq = (TQ);                                             \
      uint4 wa = G2p[(RP) * 8 + 2 * p];                               \
      uint4 wb = G2p[(RP) * 8 + 2 * p + 1];                           \
      c0 = fdot2u(wa.x, tq, c0); c1 = fdot2u(wa.y, tq, c1);           \
      c2 = fdot2u(wa.z, tq, c2); c3 = fdot2u(wa.w, tq, c3);           \
      c4 = fdot2u(wb.x, tq, c4); c5 = fdot2u(wb.y, tq, c5);           \
      c6 = fdot2u(wb.z, tq, c6); c7 = fdot2u(wb.w, tq, c7);           \
    }

    G2RP(rp0 + 0, tp0) G2RP(rp0 + 1, tp1)
    G2RP(rp0 + 2, tp2) G2RP(rp0 + 3, tp3)
    G2RP((rp0 ^ 4) + 0, XOR1U(tp0)) G2RP((rp0 ^ 4) + 1, XOR1U(tp1))
    G2RP((rp0 ^ 4) + 2, XOR1U(tp2)) G2RP((rp0 ^ 4) + 3, XOR1U(tp3))
    SBAR();
    G2RP((rp0 ^ 8) + 0, XOR2U(tp0)) G2RP((rp0 ^ 8) + 1, XOR2U(tp1))
    G2RP((rp0 ^ 8) + 2, XOR2U(tp2)) G2RP((rp0 ^ 8) + 3, XOR2U(tp3))
    G2RP((rp0 ^ 12) + 0, XOR3U(tp0)) G2RP((rp0 ^ 12) + 1, XOR3U(tp1))
    G2RP((rp0 ^ 12) + 2, XOR3U(tp2)) G2RP((rp0 ^ 12) + 3, XOR3U(tp3))
    SBAR();
#undef G2RP

    um[0] = frf(c0); um[1] = frf(c1); um[2] = frf(c2); um[3] = frf(c3);
    um[4] = frf(c4); um[5] = frf(c5); um[6] = frf(c6); um[7] = frf(c7);
  }
  lnz8r_quad(um);

  // ---- G3' via dot2 over my 4 rowpairs, then quad-reduce (DPP) ----
  float zx, zy, zz, zw;
  {
    unsigned up0 = pkrtz(um[0], um[1]);
    unsigned up1 = pkrtz(um[2], um[3]);
    unsigned up2 = pkrtz(um[4], um[5]);
    unsigned up3 = pkrtz(um[6], um[7]);
    zx = zy = zz = zw = 0.f;
    { uint4 ww = G3p[0 * 4 + p];
      zx = fdot2u(ww.x, up0, zx); zy = fdot2u(ww.y, up0, zy);
      zz = fdot2u(ww.z, up0, zz); zw = fdot2u(ww.w, up0, zw); }
    { uint4 ww = G3p[1 * 4 + p];
      zx = fdot2u(ww.x, up1, zx); zy = fdot2u(ww.y, up1, zy);
      zz = fdot2u(ww.z, up1, zz); zw = fdot2u(ww.w, up1, zw); }
    { uint4 ww = G3p[2 * 4 + p];
      zx = fdot2u(ww.x, up2, zx); zy = fdot2u(ww.y, up2, zy);
      zz = fdot2u(ww.z, up2, zz); zw = fdot2u(ww.w, up2, zw); }
    { uint4 ww = G3p[3 * 4 + p];
      zx = fdot2u(ww.x, up3, zx); zy = fdot2u(ww.y, up3, zy);
      zz = fdot2u(ww.z, up3, zz); zw = fdot2u(ww.w, up3, zw); }
  }

  const float NL2E = -1.4426950408889634f;  // -log2(e)
  float4 b2v  = *(const float4*)w->b2;
  float4 gb3v = *(const float4*)w->gb3;
  zx += XOR1(zx); zx += XOR2(zx);
  zy += XOR1(zy); zy += XOR2(zy);
  zz += XOR1(zz); zz += XOR2(zz);
  zw += XOR1(zw); zw += XOR2(zw);
  mx += XOR1(mx); mx += XOR2(mx);
  my += XOR1(my); my += XOR2(my);
  mz += XOR1(mz); mz += XOR2(mz);
  mw += XOR1(mw); mw += XOR2(mw);
  zx += gb3v.x; zy += gb3v.y; zz += gb3v.z; zw += gb3v.w;
  out[0] = (mx + b2v.x) * __builtin_amdgcn_exp2f(NL2E * zx * zx);
  out[1] = (my + b2v.y) * __builtin_amdgcn_exp2f(NL2E * zy * zy);
  out[2] = (mz + b2v.z) * __builtin_amdgcn_exp2f(NL2E * zz * zz);
  out[3] = (mw + b2v.w) * __builtin_amdgcn_exp2f(NL2E * zw * zw);
}

__global__ __launch_bounds__(256, 2) void ode_kernel(
    const float* __restrict__ s_grid, const float* __restrict__ y0,
    const float* __restrict__ W1, const float* __restrict__ b1,
    const float* __restrict__ W2, const float* __restrict__ b2,
    const float* __restrict__ G1, const float* __restrict__ gb1,
    const float* __restrict__ l1g, const float* __restrict__ l1b,
    const float* __restrict__ G2, const float* __restrict__ gb2,
    const float* __restrict__ l2g, const float* __restrict__ l2b,
    const float* __restrict__ G3, const float* __restrict__ gb3,
    float* __restrict__ out, int T, int B) {
  __shared__ WS w;
  __shared__ float sg[512];
  const int tx = threadIdx.x;
  const float TL2E = 2.8853900817779268f;   // 2*log2(e)

  // G2h: f16 rowpair-pack of G2' = (l1g o rows) * 2log2e, RTN
  for (int i = tx; i < 512; i += 256) {
    const int rp = i >> 5, c = i & 31;
    w.G2h[i] = pkrn(G2[(2 * rp) * 32 + c] * l1g[2 * rp] * TL2E,
                    G2[(2 * rp + 1) * 32 + c] * l1g[2 * rp + 1] * TL2E);
  }
  if (tx < 64) {
    const int c = tx >> 1, pr = tx & 1;
    w.W1h[tx] = pkrn(W1[(2 * pr) * 32 + c] * TL2E,
                     W1[(2 * pr + 1) * 32 + c] * TL2E);
    w.G1h[tx] = pkrn(G1[(2 * pr) * 32 + c] * TL2E,
                     G1[(2 * pr + 1) * 32 + c] * TL2E);
    const int s = tx >> 2, cc = tx & 3;
    const int rp = (s & 3) * 4 + (s >> 2);
    w.W2h[tx] = pkrn(-2.0f * W2[(2 * rp) * 4 + cc],
                     -2.0f * W2[(2 * rp + 1) * 4 + cc]);
    w.G3h[tx] = pkrn(G3[(2 * rp) * 4 + cc] * l2g[2 * rp],
                     G3[(2 * rp + 1) * 4 + cc] * l2g[2 * rp + 1]);
  }
  if (tx < 32) {
    w.b1[tx]  = b1[tx]  * TL2E;
    w.gb1[tx] = gb1[tx] * TL2E;
    float acc = gb2[tx];                      // LN1 affine fold (bias)
    for (int r = 0; r < 32; ++r) acc = fmaf(l1b[r], G2[r * 32 + tx], acc);
    w.gb2[tx] = acc * TL2E;
  }
  if (tx < 16) {
    // CS2[p*4+c] = colsum of W2 rows 8p..8p+7, col c (f32)
    const int pp = tx >> 2, cc = tx & 3;
    float acc = 0.f;
    for (int r = 0; r < 8; ++r) acc += W2[(8 * pp + r) * 4 + cc];
    w.CS2[tx] = acc;
  }
  if (tx < 4) {
    w.b2[tx] = b2[tx];
    float acc = gb3[tx];                      // LN2 affine fold (bias)
    for (int r = 0; r < 32; ++r) acc = fmaf(l2b[r], G3[r * 4 + tx], acc);
    w.gb3[tx] = acc;
  }
  for (int i = tx; i < T && i < 512; i += 256) sg[i] = s_grid[i];
  __syncthreads();

  const int tid = blockIdx.x * 256 + tx;
  const int sys = tid >> 2;   // one system per 4-lane quad
  const int p   = tid & 3;    // my column/row quarter
  if (sys >= B) return;

  float4 y0v = ((const float4*)y0)[sys];
  float y[4] = {y0v.x, y0v.y, y0v.z, y0v.w};

  // coalesced component store: lane p stores component p at flat idx t*4B+tid
  {
    float yv = (p == 0) ? y[0] : ((p == 1) ? y[1] : ((p == 2) ? y[2] : y[3]));
    out[tid] = yv;
  }

  #pragma unroll 1
  for (int t = 0; t < T - 1; ++t) {
    const float h = sg[t + 1] - sg[t];
    float k[4], ksum[4], yt[4];

    fode4(&w, p, y, k);
    #pragma unroll
    for (int c = 0; c < 4; ++c) { ksum[c] = k[c]; yt[c] = fmaf(0.5f * h, k[c], y[c]); }
    SBAR();
    fode4(&w, p, yt, k);
    #pragma unroll
    for (int c = 0; c < 4; ++c) { ksum[c] = fmaf(2.0f, k[c], ksum[c]); yt[c] = fmaf(0.5f * h, k[c], y[c]); }
    SBAR();
    fode4(&w, p, yt, k);
    #pragma unroll
    for (int c = 0; c < 4; ++c) { ksum[c] = fmaf(2.0f, k[c], ksum[c]); yt[c] = fmaf(h, k[c], y[c]); }
    SBAR();
    fode4(&w, p, yt, k);
    #pragma unroll
    for (int c = 0; c < 4; ++c)
      y[c] = fmaf(h * (1.0f / 6.0f), ksum[c] + k[c], y[c]);

    float yv = (p == 0) ? y[0] : ((p == 1) ? y[1] : ((p == 2) ? y[2] : y[3]));
    out[(size_t)(t + 1) * 4 * B + tid] = yv;
  }
}

extern "C" void kernel_launch(void* const* d_in, const int* in_sizes, int n_in,
                              void* d_out, int out_size, void* d_ws, size_t ws_size,
                              hipStream_t stream) {
  const float* s_grid = (const float*)d_in[0];
  const float* y0     = (const float*)d_in[1];
  const float* W1     = (const float*)d_in[2];
  const float* b1     = (const float*)d_in[3];
  const float* W2     = (const float*)d_in[4];
  const float* b2     = (const float*)d_in[5];
  const float* G1     = (const float*)d_in[6];
  const float* gb1    = (const float*)d_in[7];
  const float* l1g    = (const float*)d_in[8];
  const float* l1b    = (const float*)d_in[9];
  const float* G2     = (const float*)d_in[10];
  const float* gb2    = (const float*)d_in[11];
  const float* l2g    = (const float*)d_in[12];
  const float* l2b    = (const float*)d_in[13];
  const float* G3     = (const float*)d_in[14];
  const float* gb3    = (const float*)d_in[15];

  const int T = in_sizes[0];
  const int B = in_sizes[1] / 4;

  const long long threads = 4LL * B;   // 4 lanes per system -> 4 waves/SIMD
  dim3 block(256);
  dim3 grid((unsigned)((threads + 255) / 256));
  hipLaunchKernelGGL(ode_kernel, grid, block, 0, stream,
                     s_grid, y0, W1, b1, W2, b2, G1, gb1, l1g, l1b,
                     G2, gb2, l2g, l2b, G3, gb3, (float*)d_out, T, B);
}

// Round 19
// 2598.240 us; speedup vs baseline: 25.0431x; 1.4149x over previous
//
#include <hip/hip_runtime.h>
#include <math.h>

typedef _Float16 half2v __attribute__((ext_vector_type(2)));
typedef _Float16 half8  __attribute__((ext_vector_type(8)));
typedef float    f32x4  __attribute__((ext_vector_type(4)));

#define EPSV 1e-5f
#define SBAR() __builtin_amdgcn_sched_barrier(0)

// Cross-lane within a 4-lane quad via DPP quad_perm (pure VALU, 1 cyc).
template <int CTRL>
__device__ __forceinline__ float qp(float x) {
  return __int_as_float(
      __builtin_amdgcn_update_dpp(0, __float_as_int(x), CTRL, 0xF, 0xF, true));
}
#define XOR1(x) qp<0xB1>(x)   // quad_perm [1,0,3,2]
#define XOR2(x) qp<0x4E>(x)   // quad_perm [2,3,0,1]

// R19: G2 layer moved to the (idle) MFMA pipe. Per wave-eval the 16 quads'
// G2 matmul = 2 x v_mfma_f32_16x16x32_f16 (A = G2'^T staged once into 8
// VGPRs; B = t in frag layout via 4 shfl; C = folded gb2' bias). Deletes
// 32 LDS reads + 128 dot2 + 12 DPP per lane-eval (~30% of issue slots).
// Everything else (mag-net, G1, G3, LN r-form, folds) as R18.
struct __align__(16) WS {
  unsigned W1h[64]; float b1[32]; unsigned W2h[64]; float b2[4];
  float CS2[16];    // [p][c]: colsum of W2 rows 8p..8p+7 (f32)
  unsigned G1h[64]; float gb1[32];
  unsigned G2h[512]; float gb2[32];
  unsigned G3h[64]; float gb3[4];
};

// f32 += dot(f16pair(w), f16pair(t)) -- v_dot2_f32_f16.
__device__ __forceinline__ float fdot2u(unsigned wbits, unsigned tbits, float acc) {
#if __has_builtin(__builtin_amdgcn_fdot2)
  return __builtin_amdgcn_fdot2(__builtin_bit_cast(half2v, wbits),
                                __builtin_bit_cast(half2v, tbits), acc, false);
#else
  half2v wv = __builtin_bit_cast(half2v, wbits);
  half2v tv = __builtin_bit_cast(half2v, tbits);
  acc = fmaf((float)wv.x, (float)tv.x, acc);
  return fmaf((float)wv.y, (float)tv.y, acc);
#endif
}

__device__ __forceinline__ unsigned pkrtz(float lo, float hi) {
  return __builtin_bit_cast(unsigned, __builtin_amdgcn_cvt_pkrtz(lo, hi));
}
// round-to-nearest pack (staging only)
__device__ __forceinline__ unsigned pkrn(float lo, float hi) {
  half2v h;
  h.x = (_Float16)lo;
  h.y = (_Float16)hi;
  return __builtin_bit_cast(unsigned, h);
}

// r-form: r = rcp(exp2(a)+1), a pre-scaled by 2*log2(e). tanh(x) = 1 - 2r.
__device__ __forceinline__ float frf(float a) {
  float e = __builtin_amdgcn_exp2f(a);
  return __builtin_amdgcn_rcpf(e + 1.0f);
}

// r-form LN normalize, 8 r-values/lane across a QUAD (DPP reduce).
__device__ __forceinline__ void lnz8r_quad(float* rv) {
  float S = 0.f, SS = 0.f;
  #pragma unroll
  for (int i = 0; i < 8; ++i) { S += rv[i]; SS = fmaf(rv[i], rv[i], SS); }
  S += XOR1(S);  SS += XOR1(SS);
  S += XOR2(S);  SS += XOR2(SS);
  float m   = fmaf(-0.0625f, S, 1.0f);
  float Et2 = fmaf(0.125f, SS - S, 1.0f);
  float v   = fmaf(-m, m, Et2);
  float rr  = __frsqrt_rn(v + EPSV);
  float c1  = -2.0f * rr;
  float c0  = fmaf(-m, rr, rr);
  #pragma unroll
  for (int i = 0; i < 8; ++i) rv[i] = fmaf(rv[i], c1, c0);
}

// f-eval: lane p of each quad owns cols/rows [8p,8p+8) except the G2 layer,
// which runs on the MFMA pipe in fragment layout (system = col = wl&15).
__device__ __forceinline__ void fode4(const WS* w, int p, int wl,
                                      half8 ga0, half8 ga1,
                                      f32x4 gc0, f32x4 gc1,
                                      const float y[4], float out[4]) {
  const uint4*  W1p  = (const uint4*)w->W1h;
  const float4* b1v  = (const float4*)w->b1;
  const uint4*  W2p  = (const uint4*)w->W2h;   // staged -2*W2
  const uint4*  G1p  = (const uint4*)w->G1h;
  const float4* gb1v = (const float4*)w->gb1;
  const uint4*  G3p  = (const uint4*)w->G3h;

  const unsigned yp0 = pkrtz(y[0], y[1]);
  const unsigned yp1 = pkrtz(y[2], y[3]);

  // ---- magnitude net: h = 1-2r absorbed via -2*W2 + colsum init ----
  float mx, my, mz, mw;
  {
    float4 bb0 = b1v[2 * p], bb1 = b1v[2 * p + 1];
    uint4 wa0 = W1p[4 * p + 0], wa1 = W1p[4 * p + 1];
    uint4 wa2 = W1p[4 * p + 2], wa3 = W1p[4 * p + 3];
    float a0 = fdot2u(wa0.y, yp1, fdot2u(wa0.x, yp0, bb0.x));
    float a1 = fdot2u(wa0.w, yp1, fdot2u(wa0.z, yp0, bb0.y));
    float a2 = fdot2u(wa1.y, yp1, fdot2u(wa1.x, yp0, bb0.z));
    float a3 = fdot2u(wa1.w, yp1, fdot2u(wa1.z, yp0, bb0.w));
    float a4 = fdot2u(wa2.y, yp1, fdot2u(wa2.x, yp0, bb1.x));
    float a5 = fdot2u(wa2.w, yp1, fdot2u(wa2.z, yp0, bb1.y));
    float a6 = fdot2u(wa3.y, yp1, fdot2u(wa3.x, yp0, bb1.z));
    float a7 = fdot2u(wa3.w, yp1, fdot2u(wa3.z, yp0, bb1.w));
    unsigned rp_0 = pkrtz(frf(a0), frf(a1));
    unsigned rp_1 = pkrtz(frf(a2), frf(a3));
    unsigned rp_2 = pkrtz(frf(a4), frf(a5));
    unsigned rp_3 = pkrtz(frf(a6), frf(a7));
    const float4 cs = ((const float4*)w->CS2)[p];
    mx = cs.x; my = cs.y; mz = cs.z; mw = cs.w;
    { uint4 ww = W2p[0 * 4 + p];
      mx = fdot2u(ww.x, rp_0, mx); my = fdot2u(ww.y, rp_0, my);
      mz = fdot2u(ww.z, rp_0, mz); mw = fdot2u(ww.w, rp_0, mw); }
    { uint4 ww = W2p[1 * 4 + p];
      mx = fdot2u(ww.x, rp_1, mx); my = fdot2u(ww.y, rp_1, my);
      mz = fdot2u(ww.z, rp_1, mz); mw = fdot2u(ww.w, rp_1, mw); }
    { uint4 ww = W2p[2 * 4 + p];
      mx = fdot2u(ww.x, rp_2, mx); my = fdot2u(ww.y, rp_2, my);
      mz = fdot2u(ww.z, rp_2, mz); mw = fdot2u(ww.w, rp_2, mw); }
    { uint4 ww = W2p[3 * 4 + p];
      mx = fdot2u(ww.x, rp_3, mx); my = fdot2u(ww.y, rp_3, my);
      mz = fdot2u(ww.z, rp_3, mz); mw = fdot2u(ww.w, rp_3, mw); }
    SBAR();
  }

  // ---- gating layer 1: r-values, then LN-normalize in r-form (quad) ----
  float tm[8];
  {
    float4 bb0 = gb1v[2 * p], bb1 = gb1v[2 * p + 1];
    uint4 wa0 = G1p[4 * p + 0], wa1 = G1p[4 * p + 1];
    uint4 wa2 = G1p[4 * p + 2], wa3 = G1p[4 * p + 3];
    tm[0] = frf(fdot2u(wa0.y, yp1, fdot2u(wa0.x, yp0, bb0.x)));
    tm[1] = frf(fdot2u(wa0.w, yp1, fdot2u(wa0.z, yp0, bb0.y)));
    tm[2] = frf(fdot2u(wa1.y, yp1, fdot2u(wa1.x, yp0, bb0.z)));
    tm[3] = frf(fdot2u(wa1.w, yp1, fdot2u(wa1.z, yp0, bb0.w)));
    tm[4] = frf(fdot2u(wa2.y, yp1, fdot2u(wa2.x, yp0, bb1.x)));
    tm[5] = frf(fdot2u(wa2.w, yp1, fdot2u(wa2.z, yp0, bb1.y)));
    tm[6] = frf(fdot2u(wa3.y, yp1, fdot2u(wa3.x, yp0, bb1.z)));
    tm[7] = frf(fdot2u(wa3.w, yp1, fdot2u(wa3.z, yp0, bb1.w)));
  }
  lnz8r_quad(tm);

  // ---- G2 on the MFMA pipe ----
  unsigned up0, up1, up2, up3;   // u (post-LN, f16 pairs) back in quad layout
  {
    // pack normalized t (features 8p..8p+8 of my system) to f16 pairs
    unsigned tp0 = pkrtz(tm[0], tm[1]);
    unsigned tp1 = pkrtz(tm[2], tm[3]);
    unsigned tp2 = pkrtz(tm[4], tm[5]);
    unsigned tp3 = pkrtz(tm[6], tm[7]);

    // B-frag gather: lane wl needs system (wl&15)'s feature-block (wl>>4),
    // held by quad-lane 4*(wl&15) + (wl>>4).
    const int bsrc = ((wl & 15) << 2) | (wl >> 4);
    uint4 bu;
    bu.x = __shfl(tp0, bsrc);
    bu.y = __shfl(tp1, bsrc);
    bu.z = __shfl(tp2, bsrc);
    bu.w = __shfl(tp3, bsrc);
    half8 bf = __builtin_bit_cast(half8, bu);

    // D = G2'^T (A, staged) x t (B) + gb2' (C). D: col=system=wl&15,
    // row=out-feature=(wl>>4)*4+reg (tile0: 0..15, tile1: 16..31).
    f32x4 d0 = __builtin_amdgcn_mfma_f32_16x16x32_f16(ga0, bf, gc0, 0, 0, 0);
    f32x4 d1 = __builtin_amdgcn_mfma_f32_16x16x32_f16(ga1, bf, gc1, 0, 0, 0);

    float u0 = frf(d0.x), u1 = frf(d0.y), u2 = frf(d0.z), u3 = frf(d0.w);
    float u4 = frf(d1.x), u5 = frf(d1.y), u6 = frf(d1.z), u7 = frf(d1.w);

    // r-form LN in D-layout: features of my system live on lanes
    // {wl, wl^16, wl^32, wl^48}.
    float S = u0 + u1 + u2 + u3 + u4 + u5 + u6 + u7;
    float SS = u0*u0 + u1*u1 + u2*u2 + u3*u3 + u4*u4 + u5*u5 + u6*u6 + u7*u7;
    S += __shfl_xor(S, 16);  SS += __shfl_xor(SS, 16);
    S += __shfl_xor(S, 32);  SS += __shfl_xor(SS, 32);
    float m   = fmaf(-0.0625f, S, 1.0f);
    float Et2 = fmaf(0.125f, SS - S, 1.0f);
    float v   = fmaf(-m, m, Et2);
    float rr  = __frsqrt_rn(v + EPSV);
    float c1  = -2.0f * rr;
    float c0  = fmaf(-m, rr, rr);
    u0 = fmaf(u0, c1, c0); u1 = fmaf(u1, c1, c0);
    u2 = fmaf(u2, c1, c0); u3 = fmaf(u3, c1, c0);
    u4 = fmaf(u4, c1, c0); u5 = fmaf(u5, c1, c0);
    u6 = fmaf(u6, c1, c0); u7 = fmaf(u7, c1, c0);

    // pack: P0={4g,4g+1} P1={4g+2,4g+3} P2={16+4g,..} P3 (g = wl>>4)
    unsigned P0 = pkrtz(u0, u1), P1 = pkrtz(u2, u3);
    unsigned P2 = pkrtz(u4, u5), P3 = pkrtz(u6, u7);

    // scatter back to quad layout: dest quad-lane (s=wl>>2, pq=wl&3) needs
    // features 8pq..8pq+8 of system s = {P_a,P_a+1} of lanes srcA, srcB.
    const int s_  = wl >> 2;
    const int pq  = wl & 3;
    const int srcA = s_ + ((pq & 1) ? 32 : 0);
    const int srcB = srcA + 16;
    unsigned tA0 = __shfl(P0, srcA), tA1 = __shfl(P1, srcA);
    unsigned tA2 = __shfl(P2, srcA), tA3 = __shfl(P3, srcA);
    unsigned tB0 = __shfl(P0, srcB), tB1 = __shfl(P1, srcB);
    unsigned tB2 = __shfl(P2, srcB), tB3 = __shfl(P3, srcB);
    const bool lo = (pq < 2);
    up0 = lo ? tA0 : tA2;
    up1 = lo ? tA1 : tA3;
    up2 = lo ? tB0 : tB2;
    up3 = lo ? tB1 : tB3;
    SBAR();
  }

  // ---- G3' via dot2 over my 4 rowpairs, then quad-reduce (DPP) ----
  float zx, zy, zz, zw;
  {
    zx = zy = zz = zw = 0.f;
    { uint4 ww = G3p[0 * 4 + p];
      zx = fdot2u(ww.x, up0, zx); zy = fdot2u(ww.y, up0, zy);
      zz = fdot2u(ww.z, up0, zz); zw = fdot2u(ww.w, up0, zw); }
    { uint4 ww = G3p[1 * 4 + p];
      zx = fdot2u(ww.x, up1, zx); zy = fdot2u(ww.y, up1, zy);
      zz = fdot2u(ww.z, up1, zz); zw = fdot2u(ww.w, up1, zw); }
    { uint4 ww = G3p[2 * 4 + p];
      zx = fdot2u(ww.x, up2, zx); zy = fdot2u(ww.y, up2, zy);
      zz = fdot2u(ww.z, up2, zz); zw = fdot2u(ww.w, up2, zw); }
    { uint4 ww = G3p[3 * 4 + p];
      zx = fdot2u(ww.x, up3, zx); zy = fdot2u(ww.y, up3, zy);
      zz = fdot2u(ww.z, up3, zz); zw = fdot2u(ww.w, up3, zw); }
  }

  const float NL2E = -1.4426950408889634f;  // -log2(e)
  float4 b2v  = *(const float4*)w->b2;
  float4 gb3v = *(const float4*)w->gb3;
  zx += XOR1(zx); zx += XOR2(zx);
  zy += XOR1(zy); zy += XOR2(zy);
  zz += XOR1(zz); zz += XOR2(zz);
  zw += XOR1(zw); zw += XOR2(zw);
  mx += XOR1(mx); mx += XOR2(mx);
  my += XOR1(my); my += XOR2(my);
  mz += XOR1(mz); mz += XOR2(mz);
  mw += XOR1(mw); mw += XOR2(mw);
  zx += gb3v.x; zy += gb3v.y; zz += gb3v.z; zw += gb3v.w;
  out[0] = (mx + b2v.x) * __builtin_amdgcn_exp2f(NL2E * zx * zx);
  out[1] = (my + b2v.y) * __builtin_amdgcn_exp2f(NL2E * zy * zy);
  out[2] = (mz + b2v.z) * __builtin_amdgcn_exp2f(NL2E * zz * zz);
  out[3] = (mw + b2v.w) * __builtin_amdgcn_exp2f(NL2E * zw * zw);
}

__global__ __launch_bounds__(256, 2) void ode_kernel(
    const float* __restrict__ s_grid, const float* __restrict__ y0,
    const float* __restrict__ W1, const float* __restrict__ b1,
    const float* __restrict__ W2, const float* __restrict__ b2,
    const float* __restrict__ G1, const float* __restrict__ gb1,
    const float* __restrict__ l1g, const float* __restrict__ l1b,
    const float* __restrict__ G2, const float* __restrict__ gb2,
    const float* __restrict__ l2g, const float* __restrict__ l2b,
    const float* __restrict__ G3, const float* __restrict__ gb3,
    float* __restrict__ out, int T, int B) {
  __shared__ WS w;
  __shared__ float sg[512];
  const int tx = threadIdx.x;
  const float TL2E = 2.8853900817779268f;   // 2*log2(e)

  // G2h: f16 rowpair-pack of G2' = (l1g o rows) * 2log2e, RTN
  for (int i = tx; i < 512; i += 256) {
    const int rp = i >> 5, c = i & 31;
    w.G2h[i] = pkrn(G2[(2 * rp) * 32 + c] * l1g[2 * rp] * TL2E,
                    G2[(2 * rp + 1) * 32 + c] * l1g[2 * rp + 1] * TL2E);
  }
  if (tx < 64) {
    const int c = tx >> 1, pr = tx & 1;
    w.W1h[tx] = pkrn(W1[(2 * pr) * 32 + c] * TL2E,
                     W1[(2 * pr + 1) * 32 + c] * TL2E);
    w.G1h[tx] = pkrn(G1[(2 * pr) * 32 + c] * TL2E,
                     G1[(2 * pr + 1) * 32 + c] * TL2E);
    const int s = tx >> 2, cc = tx & 3;
    const int rp = (s & 3) * 4 + (s >> 2);
    w.W2h[tx] = pkrn(-2.0f * W2[(2 * rp) * 4 + cc],
                     -2.0f * W2[(2 * rp + 1) * 4 + cc]);
    w.G3h[tx] = pkrn(G3[(2 * rp) * 4 + cc] * l2g[2 * rp],
                     G3[(2 * rp + 1) * 4 + cc] * l2g[2 * rp + 1]);
  }
  if (tx < 32) {
    w.b1[tx]  = b1[tx]  * TL2E;
    w.gb1[tx] = gb1[tx] * TL2E;
    float acc = gb2[tx];                      // LN1 affine fold (bias)
    for (int r = 0; r < 32; ++r) acc = fmaf(l1b[r], G2[r * 32 + tx], acc);
    w.gb2[tx] = acc * TL2E;
  }
  if (tx < 16) {
    const int pp = tx >> 2, cc = tx & 3;
    float acc = 0.f;
    for (int r = 0; r < 8; ++r) acc += W2[(8 * pp + r) * 4 + cc];
    w.CS2[tx] = acc;
  }
  if (tx < 4) {
    w.b2[tx] = b2[tx];
    float acc = gb3[tx];                      // LN2 affine fold (bias)
    for (int r = 0; r < 32; ++r) acc = fmaf(l2b[r], G3[r * 4 + tx], acc);
    w.gb3[tx] = acc;
  }
  for (int i = tx; i < T && i < 512; i += 256) sg[i] = s_grid[i];
  __syncthreads();

  const int tid = blockIdx.x * 256 + tx;
  const int sys = tid >> 2;   // one system per 4-lane quad
  const int p   = tid & 3;    // my column/row quarter
  if (sys >= B) return;

  // ---- one-time MFMA operand staging (A = G2'^T, C = gb2' bias) ----
  const int wl = tx & 63;         // lane in wave
  const int gg = wl >> 4;         // my k-block / row-group
  const int nn = wl & 15;         // my A-row (out-feature) / B-col (system)
  uint4 a0u, a1u;
  a0u.x = w.G2h[(4 * gg + 0) * 32 + nn];
  a0u.y = w.G2h[(4 * gg + 1) * 32 + nn];
  a0u.z = w.G2h[(4 * gg + 2) * 32 + nn];
  a0u.w = w.G2h[(4 * gg + 3) * 32 + nn];
  a1u.x = w.G2h[(4 * gg + 0) * 32 + nn + 16];
  a1u.y = w.G2h[(4 * gg + 1) * 32 + nn + 16];
  a1u.z = w.G2h[(4 * gg + 2) * 32 + nn + 16];
  a1u.w = w.G2h[(4 * gg + 3) * 32 + nn + 16];
  half8 ga0 = __builtin_bit_cast(half8, a0u);
  half8 ga1 = __builtin_bit_cast(half8, a1u);
  f32x4 gc0, gc1;
  gc0.x = w.gb2[4 * gg + 0]; gc0.y = w.gb2[4 * gg + 1];
  gc0.z = w.gb2[4 * gg + 2]; gc0.w = w.gb2[4 * gg + 3];
  gc1.x = w.gb2[16 + 4 * gg + 0]; gc1.y = w.gb2[16 + 4 * gg + 1];
  gc1.z = w.gb2[16 + 4 * gg + 2]; gc1.w = w.gb2[16 + 4 * gg + 3];

  float4 y0v = ((const float4*)y0)[sys];
  float y[4] = {y0v.x, y0v.y, y0v.z, y0v.w};

  // coalesced component store: lane p stores component p at flat idx t*4B+tid
  {
    float yv = (p == 0) ? y[0] : ((p == 1) ? y[1] : ((p == 2) ? y[2] : y[3]));
    out[tid] = yv;
  }

  #pragma unroll 1
  for (int t = 0; t < T - 1; ++t) {
    const float h = sg[t + 1] - sg[t];
    float k[4], ksum[4], yt[4];

    fode4(&w, p, wl, ga0, ga1, gc0, gc1, y, k);
    #pragma unroll
    for (int c = 0; c < 4; ++c) { ksum[c] = k[c]; yt[c] = fmaf(0.5f * h, k[c], y[c]); }
    SBAR();
    fode4(&w, p, wl, ga0, ga1, gc0, gc1, yt, k);
    #pragma unroll
    for (int c = 0; c < 4; ++c) { ksum[c] = fmaf(2.0f, k[c], ksum[c]); yt[c] = fmaf(0.5f * h, k[c], y[c]); }
    SBAR();
    fode4(&w, p, wl, ga0, ga1, gc0, gc1, yt, k);
    #pragma unroll
    for (int c = 0; c < 4; ++c) { ksum[c] = fmaf(2.0f, k[c], ksum[c]); yt[c] = fmaf(h, k[c], y[c]); }
    SBAR();
    fode4(&w, p, wl, ga0, ga1, gc0, gc1, yt, k);
    #pragma unroll
    for (int c = 0; c < 4; ++c)
      y[c] = fmaf(h * (1.0f / 6.0f), ksum[c] + k[c], y[c]);

    float yv = (p == 0) ? y[0] : ((p == 1) ? y[1] : ((p == 2) ? y[2] : y[3]));
    out[(size_t)(t + 1) * 4 * B + tid] = yv;
  }
}

extern "C" void kernel_launch(void* const* d_in, const int* in_sizes, int n_in,
                              void* d_out, int out_size, void* d_ws, size_t ws_size,
                              hipStream_t stream) {
  const float* s_grid = (const float*)d_in[0];
  const float* y0     = (const float*)d_in[1];
  const float* W1     = (const float*)d_in[2];
  const float* b1     = (const float*)d_in[3];
  const float* W2     = (const float*)d_in[4];
  const float* b2     = (const float*)d_in[5];
  const float* G1     = (const float*)d_in[6];
  const float* gb1    = (const float*)d_in[7];
  const float* l1g    = (const float*)d_in[8];
  const float* l1b    = (const float*)d_in[9];
  const float* G2     = (const float*)d_in[10];
  const float* gb2    = (const float*)d_in[11];
  const float* l2g    = (const float*)d_in[12];
  const float* l2b    = (const float*)d_in[13];
  const float* G3     = (const float*)d_in[14];
  const float* gb3    = (const float*)d_in[15];

  const int T = in_sizes[0];
  const int B = in_sizes[1] / 4;

  const long long threads = 4LL * B;   // 4 lanes per system -> 4 waves/SIMD
  dim3 block(256);
  dim3 grid((unsigned)((threads + 255) / 256));
  hipLaunchKernelGGL(ode_kernel, grid, block, 0, stream,
                     s_grid, y0, W1, b1, W2, b2, G1, gb1, l1g, l1b,
                     G2, gb2, l2g, l2b, G3, gb3, (float*)d_out, T, B);
}

// Round 20
// 1826.930 us; speedup vs baseline: 35.6160x; 1.4222x over previous
//
#include <hip/hip_runtime.h>
#include <math.h>

typedef _Float16 half2v __attribute__((ext_vector_type(2)));
typedef _Float16 half8  __attribute__((ext_vector_type(8)));
typedef float    f32x4  __attribute__((ext_vector_type(4)));

#define EPSV 1e-5f
#define SBAR() __builtin_amdgcn_sched_barrier(0)
#define MFMA(A, B, C) __builtin_amdgcn_mfma_f32_16x16x32_f16((A), (B), (C), 0, 0, 0)

// R20: FULL-MFMA pipeline with zero-shuffle hand-offs. Systems live at
// columns (lane n = wl&15, 4 row-group lanes g = wl>>4 per system).
// Every A-tile is staged (once, into registers) with ROWS PERMUTED as
// perm(r) = (r>>2)*8 + (r&3) (tile0) / +4 (tile1), so lane (g,n)'s D output
// = features 8g..8g+7 of system n = exactly its own B k-block for the NEXT
// MFMA. t->G2, h->W2, u->G3 need no cross-lane moves. y is lane-replicated
// (front B local, K zero-padded 4->32). Weights never touch LDS in the loop.
// Biases/folds ride the C operand (W2: full colsum+b2; G3: gb3 folded).
// r-form tanh + LN folds as R18; fragment mappings as verified in R19.

// f32 pair -> packed f16 (RTZ, per-eval)
__device__ __forceinline__ unsigned pkrtz(float lo, float hi) {
  return __builtin_bit_cast(unsigned, __builtin_amdgcn_cvt_pkrtz(lo, hi));
}
// round-to-nearest pack (staging only)
__device__ __forceinline__ unsigned pkrn(float lo, float hi) {
  half2v h;
  h.x = (_Float16)lo;
  h.y = (_Float16)hi;
  return __builtin_bit_cast(unsigned, h);
}
// r-form: r = rcp(exp2(a)+1), a pre-scaled by 2*log2(e). tanh(x) = 1 - 2r.
__device__ __forceinline__ float frf(float a) {
  float e = __builtin_amdgcn_exp2f(a);
  return __builtin_amdgcn_rcpf(e + 1.0f);
}
__device__ __forceinline__ half8 h8(uint4 u) {
  return __builtin_bit_cast(half8, u);
}

__global__ __launch_bounds__(256, 2) void ode_kernel(
    const float* __restrict__ s_grid, const float* __restrict__ y0,
    const float* __restrict__ W1, const float* __restrict__ b1,
    const float* __restrict__ W2, const float* __restrict__ b2,
    const float* __restrict__ G1, const float* __restrict__ gb1,
    const float* __restrict__ l1g, const float* __restrict__ l1b,
    const float* __restrict__ G2, const float* __restrict__ gb2,
    const float* __restrict__ l2g, const float* __restrict__ l2b,
    const float* __restrict__ G3, const float* __restrict__ gb3,
    float* __restrict__ out, int T, int B) {
  __shared__ float gb2p[32];
  __shared__ float gb3p[4];
  __shared__ float cs2b2[4];
  __shared__ float sg[512];
  const int tx = threadIdx.x;
  const float TL2E = 2.8853900817779268f;   // 2*log2(e)
  const float NL2E = -1.4426950408889634f;  // -log2(e)

  if (tx < 32) {
    float acc = gb2[tx];                    // LN1 affine fold (bias)
    for (int r = 0; r < 32; ++r) acc = fmaf(l1b[r], G2[r * 32 + tx], acc);
    gb2p[tx] = acc * TL2E;
  }
  if (tx < 4) {
    float a3 = gb3[tx];                     // LN2 affine fold (bias)
    for (int r = 0; r < 32; ++r) a3 = fmaf(l2b[r], G3[r * 4 + tx], a3);
    gb3p[tx] = a3;
    float cs = b2[tx];                      // r-form fold: full colsum + b2
    for (int k = 0; k < 32; ++k) cs += W2[k * 4 + tx];
    cs2b2[tx] = cs;
  }
  for (int i = tx; i < T && i < 512; i += 256) sg[i] = s_grid[i];
  __syncthreads();

  const int wl = tx & 63;
  const int g  = wl >> 4;                 // row-group / k-block
  const int n  = wl & 15;                 // system column
  const int tid = blockIdx.x * 256 + tx;
  const int sys = (tid >> 6) * 16 + n;
  if (sys >= B) return;
  const int f  = ((n >> 2) << 3) | (n & 3);   // perm(n): A-row -> feature
  const int k8 = 8 * g;

  // ---- A-frag staging (registers, once). A[row=n][k-block g]. ----
  uint4 z4; z4.x = z4.y = z4.z = z4.w = 0u;
  uint4 am0 = z4, am1 = z4, at0 = z4, at1 = z4;
  if (g == 0) {   // front layers: K=4 real (y), rest zero
    am0.x = pkrn(W1[0 * 32 + f] * TL2E, W1[1 * 32 + f] * TL2E);
    am0.y = pkrn(W1[2 * 32 + f] * TL2E, W1[3 * 32 + f] * TL2E);
    am1.x = pkrn(W1[0 * 32 + f + 4] * TL2E, W1[1 * 32 + f + 4] * TL2E);
    am1.y = pkrn(W1[2 * 32 + f + 4] * TL2E, W1[3 * 32 + f + 4] * TL2E);
    at0.x = pkrn(G1[0 * 32 + f] * TL2E, G1[1 * 32 + f] * TL2E);
    at0.y = pkrn(G1[2 * 32 + f] * TL2E, G1[3 * 32 + f] * TL2E);
    at1.x = pkrn(G1[0 * 32 + f + 4] * TL2E, G1[1 * 32 + f + 4] * TL2E);
    at1.y = pkrn(G1[2 * 32 + f + 4] * TL2E, G1[3 * 32 + f + 4] * TL2E);
  }
  // G2' = l1g-scaled * 2log2e; full K=32
  uint4 a20, a21;
  {
    const float* Gp = G2;
    a20.x = pkrn(Gp[(k8+0)*32+f]*l1g[k8+0]*TL2E, Gp[(k8+1)*32+f]*l1g[k8+1]*TL2E);
    a20.y = pkrn(Gp[(k8+2)*32+f]*l1g[k8+2]*TL2E, Gp[(k8+3)*32+f]*l1g[k8+3]*TL2E);
    a20.z = pkrn(Gp[(k8+4)*32+f]*l1g[k8+4]*TL2E, Gp[(k8+5)*32+f]*l1g[k8+5]*TL2E);
    a20.w = pkrn(Gp[(k8+6)*32+f]*l1g[k8+6]*TL2E, Gp[(k8+7)*32+f]*l1g[k8+7]*TL2E);
    const int f4 = f + 4;
    a21.x = pkrn(Gp[(k8+0)*32+f4]*l1g[k8+0]*TL2E, Gp[(k8+1)*32+f4]*l1g[k8+1]*TL2E);
    a21.y = pkrn(Gp[(k8+2)*32+f4]*l1g[k8+2]*TL2E, Gp[(k8+3)*32+f4]*l1g[k8+3]*TL2E);
    a21.z = pkrn(Gp[(k8+4)*32+f4]*l1g[k8+4]*TL2E, Gp[(k8+5)*32+f4]*l1g[k8+5]*TL2E);
    a21.w = pkrn(Gp[(k8+6)*32+f4]*l1g[k8+6]*TL2E, Gp[(k8+7)*32+f4]*l1g[k8+7]*TL2E);
  }
  // W2 (staged -2*W2, rows 0..3 = output comps) and G3' (l2g-scaled)
  uint4 aw2 = z4, ag3 = z4;
  if (n < 4) {
    aw2.x = pkrn(-2.f*W2[(k8+0)*4+n], -2.f*W2[(k8+1)*4+n]);
    aw2.y = pkrn(-2.f*W2[(k8+2)*4+n], -2.f*W2[(k8+3)*4+n]);
    aw2.z = pkrn(-2.f*W2[(k8+4)*4+n], -2.f*W2[(k8+5)*4+n]);
    aw2.w = pkrn(-2.f*W2[(k8+6)*4+n], -2.f*W2[(k8+7)*4+n]);
    ag3.x = pkrn(G3[(k8+0)*4+n]*l2g[k8+0], G3[(k8+1)*4+n]*l2g[k8+1]);
    ag3.y = pkrn(G3[(k8+2)*4+n]*l2g[k8+2], G3[(k8+3)*4+n]*l2g[k8+3]);
    ag3.z = pkrn(G3[(k8+4)*4+n]*l2g[k8+4], G3[(k8+5)*4+n]*l2g[k8+5]);
    ag3.w = pkrn(G3[(k8+6)*4+n]*l2g[k8+6], G3[(k8+7)*4+n]*l2g[k8+7]);
  }
  const half8 Am0 = h8(am0), Am1 = h8(am1), At0 = h8(at0), At1 = h8(at1);
  const half8 A20 = h8(a20), A21 = h8(a21), Aw2 = h8(aw2), Ag3 = h8(ag3);

  // ---- C-frag staging: biases per D-row (feature 8g+j / 8g+4+j) ----
  f32x4 Cm0, Cm1, Ct0, Ct1, C20, C21, Cw2, Cg3;
  Cm0.x = b1[k8+0]*TL2E; Cm0.y = b1[k8+1]*TL2E; Cm0.z = b1[k8+2]*TL2E; Cm0.w = b1[k8+3]*TL2E;
  Cm1.x = b1[k8+4]*TL2E; Cm1.y = b1[k8+5]*TL2E; Cm1.z = b1[k8+6]*TL2E; Cm1.w = b1[k8+7]*TL2E;
  Ct0.x = gb1[k8+0]*TL2E; Ct0.y = gb1[k8+1]*TL2E; Ct0.z = gb1[k8+2]*TL2E; Ct0.w = gb1[k8+3]*TL2E;
  Ct1.x = gb1[k8+4]*TL2E; Ct1.y = gb1[k8+5]*TL2E; Ct1.z = gb1[k8+6]*TL2E; Ct1.w = gb1[k8+7]*TL2E;
  C20.x = gb2p[k8+0]; C20.y = gb2p[k8+1]; C20.z = gb2p[k8+2]; C20.w = gb2p[k8+3];
  C21.x = gb2p[k8+4]; C21.y = gb2p[k8+5]; C21.z = gb2p[k8+6]; C21.w = gb2p[k8+7];
  Cw2.x = cs2b2[0]; Cw2.y = cs2b2[1]; Cw2.z = cs2b2[2]; Cw2.w = cs2b2[3];
  Cg3.x = gb3p[0]; Cg3.y = gb3p[1]; Cg3.z = gb3p[2]; Cg3.w = gb3p[3];

  // ---- state ----
  float4 yv0 = ((const float4*)y0)[sys];
  float y[4] = {yv0.x, yv0.y, yv0.z, yv0.w};

  // lane stores component g of its system
  {
    float s0 = (g == 0) ? y[0] : ((g == 1) ? y[1] : ((g == 2) ? y[2] : y[3]));
    out[(size_t)sys * 4 + g] = s0;
  }

  const bool g0 = (g == 0);

  auto feval = [&](const float yv[4], float kv[4]) {
    unsigned yp0 = pkrtz(yv[0], yv[1]);
    unsigned yp1 = pkrtz(yv[2], yv[3]);
    uint4 bu;
    bu.x = g0 ? yp0 : 0u;
    bu.y = g0 ? yp1 : 0u;
    bu.z = 0u; bu.w = 0u;
    half8 Bf = h8(bu);
    f32x4 dm0 = MFMA(Am0, Bf, Cm0);
    f32x4 dm1 = MFMA(Am1, Bf, Cm1);
    f32x4 dt0 = MFMA(At0, Bf, Ct0);
    f32x4 dt1 = MFMA(At1, Bf, Ct1);

    // mag hidden r-values -> B frag for W2 (local, natural k order)
    uint4 hb;
    hb.x = pkrtz(frf(dm0.x), frf(dm0.y));
    hb.y = pkrtz(frf(dm0.z), frf(dm0.w));
    hb.z = pkrtz(frf(dm1.x), frf(dm1.y));
    hb.w = pkrtz(frf(dm1.z), frf(dm1.w));
    f32x4 dmm = MFMA(Aw2, h8(hb), Cw2);   // m_c at g=0 lanes

    // t: r-values + r-form LN (stats across column lanes: xor16, xor32)
    float r0 = frf(dt0.x), r1 = frf(dt0.y), r2 = frf(dt0.z), r3 = frf(dt0.w);
    float r4 = frf(dt1.x), r5 = frf(dt1.y), r6 = frf(dt1.z), r7 = frf(dt1.w);
    {
      float S  = ((r0 + r1) + (r2 + r3)) + ((r4 + r5) + (r6 + r7));
      float SS = fmaf(r0, r0, fmaf(r1, r1, fmaf(r2, r2, fmaf(r3, r3,
                 fmaf(r4, r4, fmaf(r5, r5, fmaf(r6, r6, r7 * r7)))))));
      S += __shfl_xor(S, 16);  SS += __shfl_xor(SS, 16);
      S += __shfl_xor(S, 32);  SS += __shfl_xor(SS, 32);
      float m   = fmaf(-0.0625f, S, 1.0f);
      float Et2 = fmaf(0.125f, SS - S, 1.0f);
      float v   = fmaf(-m, m, Et2);
      float rr  = __frsqrt_rn(v + EPSV);
      float c1  = -2.0f * rr;
      float c0  = fmaf(-m, rr, rr);
      r0 = fmaf(r0, c1, c0); r1 = fmaf(r1, c1, c0);
      r2 = fmaf(r2, c1, c0); r3 = fmaf(r3, c1, c0);
      r4 = fmaf(r4, c1, c0); r5 = fmaf(r5, c1, c0);
      r6 = fmaf(r6, c1, c0); r7 = fmaf(r7, c1, c0);
    }
    uint4 tb;
    tb.x = pkrtz(r0, r1); tb.y = pkrtz(r2, r3);
    tb.z = pkrtz(r4, r5); tb.w = pkrtz(r6, r7);
    f32x4 du0 = MFMA(A20, h8(tb), C20);
    f32x4 du1 = MFMA(A21, h8(tb), C21);

    // u: r-values + r-form LN
    float u0 = frf(du0.x), u1 = frf(du0.y), u2 = frf(du0.z), u3 = frf(du0.w);
    float u4 = frf(du1.x), u5 = frf(du1.y), u6 = frf(du1.z), u7 = frf(du1.w);
    {
      float S  = ((u0 + u1) + (u2 + u3)) + ((u4 + u5) + (u6 + u7));
      float SS = fmaf(u0, u0, fmaf(u1, u1, fmaf(u2, u2, fmaf(u3, u3,
                 fmaf(u4, u4, fmaf(u5, u5, fmaf(u6, u6, u7 * u7)))))));
      S += __shfl_xor(S, 16);  SS += __shfl_xor(SS, 16);
      S += __shfl_xor(S, 32);  SS += __shfl_xor(SS, 32);
      float m   = fmaf(-0.0625f, S, 1.0f);
      float Et2 = fmaf(0.125f, SS - S, 1.0f);
      float v   = fmaf(-m, m, Et2);
      float rr  = __frsqrt_rn(v + EPSV);
      float c1  = -2.0f * rr;
      float c0  = fmaf(-m, rr, rr);
      u0 = fmaf(u0, c1, c0); u1 = fmaf(u1, c1, c0);
      u2 = fmaf(u2, c1, c0); u3 = fmaf(u3, c1, c0);
      u4 = fmaf(u4, c1, c0); u5 = fmaf(u5, c1, c0);
      u6 = fmaf(u6, c1, c0); u7 = fmaf(u7, c1, c0);
    }
    uint4 ub;
    ub.x = pkrtz(u0, u1); ub.y = pkrtz(u2, u3);
    ub.z = pkrtz(u4, u5); ub.w = pkrtz(u6, u7);
    f32x4 dz = MFMA(Ag3, h8(ub), Cg3);    // z_c (bias folded) at g=0 lanes

    // final gate (valid on g=0 lanes), then broadcast k to the column
    float kq0 = dmm.x * __builtin_amdgcn_exp2f(NL2E * dz.x * dz.x);
    float kq1 = dmm.y * __builtin_amdgcn_exp2f(NL2E * dz.y * dz.y);
    float kq2 = dmm.z * __builtin_amdgcn_exp2f(NL2E * dz.z * dz.z);
    float kq3 = dmm.w * __builtin_amdgcn_exp2f(NL2E * dz.w * dz.w);
    kv[0] = __shfl(kq0, n);
    kv[1] = __shfl(kq1, n);
    kv[2] = __shfl(kq2, n);
    kv[3] = __shfl(kq3, n);
  };

  #pragma unroll 1
  for (int t = 0; t < T - 1; ++t) {
    const float h = sg[t + 1] - sg[t];
    float k[4], ksum[4], yt[4];

    feval(y, k);
    #pragma unroll
    for (int c = 0; c < 4; ++c) { ksum[c] = k[c]; yt[c] = fmaf(0.5f * h, k[c], y[c]); }
    SBAR();
    feval(yt, k);
    #pragma unroll
    for (int c = 0; c < 4; ++c) { ksum[c] = fmaf(2.0f, k[c], ksum[c]); yt[c] = fmaf(0.5f * h, k[c], y[c]); }
    SBAR();
    feval(yt, k);
    #pragma unroll
    for (int c = 0; c < 4; ++c) { ksum[c] = fmaf(2.0f, k[c], ksum[c]); yt[c] = fmaf(h, k[c], y[c]); }
    SBAR();
    feval(yt, k);
    #pragma unroll
    for (int c = 0; c < 4; ++c)
      y[c] = fmaf(h * (1.0f / 6.0f), ksum[c] + k[c], y[c]);

    float s0 = (g == 0) ? y[0] : ((g == 1) ? y[1] : ((g == 2) ? y[2] : y[3]));
    out[(size_t)(t + 1) * 4 * B + (size_t)sys * 4 + g] = s0;
  }
}

extern "C" void kernel_launch(void* const* d_in, const int* in_sizes, int n_in,
                              void* d_out, int out_size, void* d_ws, size_t ws_size,
                              hipStream_t stream) {
  const float* s_grid = (const float*)d_in[0];
  const float* y0     = (const float*)d_in[1];
  const float* W1     = (const float*)d_in[2];
  const float* b1     = (const float*)d_in[3];
  const float* W2     = (const float*)d_in[4];
  const float* b2     = (const float*)d_in[5];
  const float* G1     = (const float*)d_in[6];
  const float* gb1    = (const float*)d_in[7];
  const float* l1g    = (const float*)d_in[8];
  const float* l1b    = (const float*)d_in[9];
  const float* G2     = (const float*)d_in[10];
  const float* gb2    = (const float*)d_in[11];
  const float* l2g    = (const float*)d_in[12];
  const float* l2b    = (const float*)d_in[13];
  const float* G3     = (const float*)d_in[14];
  const float* gb3    = (const float*)d_in[15];

  const int T = in_sizes[0];
  const int B = in_sizes[1] / 4;

  const long long threads = 4LL * B;   // 4 row-group lanes per system
  dim3 block(256);
  dim3 grid((unsigned)((threads + 255) / 256));
  hipLaunchKernelGGL(ode_kernel, grid, block, 0, stream,
                     s_grid, y0, W1, b1, W2, b2, G1, gb1, l1g, l1b,
                     G2, gb2, l2g, l2b, G3, gb3, (float*)d_out, T, B);
}

// Round 21
// 1771.842 us; speedup vs baseline: 36.7234x; 1.0311x over previous
//
#include <hip/hip_runtime.h>
#include <math.h>

typedef _Float16 half2v __attribute__((ext_vector_type(2)));
typedef _Float16 half8  __attribute__((ext_vector_type(8)));
typedef float    f32x4  __attribute__((ext_vector_type(4)));

#define EPSV 1e-5f
#define MFMA(A, B, C) __builtin_amdgcn_mfma_f32_16x16x32_f16((A), (B), (C), 0, 0, 0)

// R21 = R20 (full-MFMA zero-shuffle pipeline) +
//  * LN stats via fdot2 (r_pk . ones / r_pk . r_pk): 8 dot2 vs 15 f32 ops
//  * LN normalize via v_pk_fma_f16 on packed pairs: 4 pk_fma vs 8 fma+4 pkrtz
//  * loop SBARs removed (no LDS in loop -> nothing to fence)

__device__ __forceinline__ unsigned pkrtz(float lo, float hi) {
  return __builtin_bit_cast(unsigned, __builtin_amdgcn_cvt_pkrtz(lo, hi));
}
__device__ __forceinline__ unsigned pkrn(float lo, float hi) {
  half2v h;
  h.x = (_Float16)lo;
  h.y = (_Float16)hi;
  return __builtin_bit_cast(unsigned, h);
}
__device__ __forceinline__ float frf(float a) {
  float e = __builtin_amdgcn_exp2f(a);
  return __builtin_amdgcn_rcpf(e + 1.0f);
}
__device__ __forceinline__ half8 h8(uint4 u) {
  return __builtin_bit_cast(half8, u);
}
__device__ __forceinline__ float fdot2u(unsigned wbits, unsigned tbits, float acc) {
#if __has_builtin(__builtin_amdgcn_fdot2)
  return __builtin_amdgcn_fdot2(__builtin_bit_cast(half2v, wbits),
                                __builtin_bit_cast(half2v, tbits), acc, false);
#else
  half2v wv = __builtin_bit_cast(half2v, wbits);
  half2v tv = __builtin_bit_cast(half2v, tbits);
  acc = fmaf((float)wv.x, (float)tv.x, acc);
  return fmaf((float)wv.y, (float)tv.y, acc);
#endif
}
// packed f16 fma: t = r*c1 + c0 (v_pk_fma_f16)
__device__ __forceinline__ unsigned pkfma16(unsigned r, unsigned c1, unsigned c0) {
  half2v rv = __builtin_bit_cast(half2v, r);
  half2v a  = __builtin_bit_cast(half2v, c1);
  half2v b  = __builtin_bit_cast(half2v, c0);
  half2v o  = __builtin_elementwise_fma(rv, a, b);
  return __builtin_bit_cast(unsigned, o);
}

__global__ __launch_bounds__(256, 2) void ode_kernel(
    const float* __restrict__ s_grid, const float* __restrict__ y0,
    const float* __restrict__ W1, const float* __restrict__ b1,
    const float* __restrict__ W2, const float* __restrict__ b2,
    const float* __restrict__ G1, const float* __restrict__ gb1,
    const float* __restrict__ l1g, const float* __restrict__ l1b,
    const float* __restrict__ G2, const float* __restrict__ gb2,
    const float* __restrict__ l2g, const float* __restrict__ l2b,
    const float* __restrict__ G3, const float* __restrict__ gb3,
    float* __restrict__ out, int T, int B) {
  __shared__ float gb2p[32];
  __shared__ float gb3p[4];
  __shared__ float cs2b2[4];
  __shared__ float sg[512];
  const int tx = threadIdx.x;
  const float TL2E = 2.8853900817779268f;   // 2*log2(e)
  const float NL2E = -1.4426950408889634f;  // -log2(e)

  if (tx < 32) {
    float acc = gb2[tx];                    // LN1 affine fold (bias)
    for (int r = 0; r < 32; ++r) acc = fmaf(l1b[r], G2[r * 32 + tx], acc);
    gb2p[tx] = acc * TL2E;
  }
  if (tx < 4) {
    float a3 = gb3[tx];                     // LN2 affine fold (bias)
    for (int r = 0; r < 32; ++r) a3 = fmaf(l2b[r], G3[r * 4 + tx], a3);
    gb3p[tx] = a3;
    float cs = b2[tx];                      // r-form fold: full colsum + b2
    for (int k = 0; k < 32; ++k) cs += W2[k * 4 + tx];
    cs2b2[tx] = cs;
  }
  for (int i = tx; i < T && i < 512; i += 256) sg[i] = s_grid[i];
  __syncthreads();

  const int wl = tx & 63;
  const int g  = wl >> 4;                 // row-group / k-block
  const int n  = wl & 15;                 // system column
  const int tid = blockIdx.x * 256 + tx;
  const int sys = (tid >> 6) * 16 + n;
  if (sys >= B) return;
  const int f  = ((n >> 2) << 3) | (n & 3);   // perm(n): A-row -> feature
  const int k8 = 8 * g;

  // ---- A-frag staging (registers, once). ----
  uint4 z4; z4.x = z4.y = z4.z = z4.w = 0u;
  uint4 am0 = z4, am1 = z4, at0 = z4, at1 = z4;
  if (g == 0) {
    am0.x = pkrn(W1[0 * 32 + f] * TL2E, W1[1 * 32 + f] * TL2E);
    am0.y = pkrn(W1[2 * 32 + f] * TL2E, W1[3 * 32 + f] * TL2E);
    am1.x = pkrn(W1[0 * 32 + f + 4] * TL2E, W1[1 * 32 + f + 4] * TL2E);
    am1.y = pkrn(W1[2 * 32 + f + 4] * TL2E, W1[3 * 32 + f + 4] * TL2E);
    at0.x = pkrn(G1[0 * 32 + f] * TL2E, G1[1 * 32 + f] * TL2E);
    at0.y = pkrn(G1[2 * 32 + f] * TL2E, G1[3 * 32 + f] * TL2E);
    at1.x = pkrn(G1[0 * 32 + f + 4] * TL2E, G1[1 * 32 + f + 4] * TL2E);
    at1.y = pkrn(G1[2 * 32 + f + 4] * TL2E, G1[3 * 32 + f + 4] * TL2E);
  }
  uint4 a20, a21;
  {
    const float* Gp = G2;
    a20.x = pkrn(Gp[(k8+0)*32+f]*l1g[k8+0]*TL2E, Gp[(k8+1)*32+f]*l1g[k8+1]*TL2E);
    a20.y = pkrn(Gp[(k8+2)*32+f]*l1g[k8+2]*TL2E, Gp[(k8+3)*32+f]*l1g[k8+3]*TL2E);
    a20.z = pkrn(Gp[(k8+4)*32+f]*l1g[k8+4]*TL2E, Gp[(k8+5)*32+f]*l1g[k8+5]*TL2E);
    a20.w = pkrn(Gp[(k8+6)*32+f]*l1g[k8+6]*TL2E, Gp[(k8+7)*32+f]*l1g[k8+7]*TL2E);
    const int f4 = f + 4;
    a21.x = pkrn(Gp[(k8+0)*32+f4]*l1g[k8+0]*TL2E, Gp[(k8+1)*32+f4]*l1g[k8+1]*TL2E);
    a21.y = pkrn(Gp[(k8+2)*32+f4]*l1g[k8+2]*TL2E, Gp[(k8+3)*32+f4]*l1g[k8+3]*TL2E);
    a21.z = pkrn(Gp[(k8+4)*32+f4]*l1g[k8+4]*TL2E, Gp[(k8+5)*32+f4]*l1g[k8+5]*TL2E);
    a21.w = pkrn(Gp[(k8+6)*32+f4]*l1g[k8+6]*TL2E, Gp[(k8+7)*32+f4]*l1g[k8+7]*TL2E);
  }
  uint4 aw2 = z4, ag3 = z4;
  if (n < 4) {
    aw2.x = pkrn(-2.f*W2[(k8+0)*4+n], -2.f*W2[(k8+1)*4+n]);
    aw2.y = pkrn(-2.f*W2[(k8+2)*4+n], -2.f*W2[(k8+3)*4+n]);
    aw2.z = pkrn(-2.f*W2[(k8+4)*4+n], -2.f*W2[(k8+5)*4+n]);
    aw2.w = pkrn(-2.f*W2[(k8+6)*4+n], -2.f*W2[(k8+7)*4+n]);
    ag3.x = pkrn(G3[(k8+0)*4+n]*l2g[k8+0], G3[(k8+1)*4+n]*l2g[k8+1]);
    ag3.y = pkrn(G3[(k8+2)*4+n]*l2g[k8+2], G3[(k8+3)*4+n]*l2g[k8+3]);
    ag3.z = pkrn(G3[(k8+4)*4+n]*l2g[k8+4], G3[(k8+5)*4+n]*l2g[k8+5]);
    ag3.w = pkrn(G3[(k8+6)*4+n]*l2g[k8+6], G3[(k8+7)*4+n]*l2g[k8+7]);
  }
  const half8 Am0 = h8(am0), Am1 = h8(am1), At0 = h8(at0), At1 = h8(at1);
  const half8 A20 = h8(a20), A21 = h8(a21), Aw2 = h8(aw2), Ag3 = h8(ag3);

  // ---- C-frag staging ----
  f32x4 Cm0, Cm1, Ct0, Ct1, C20, C21, Cw2, Cg3;
  Cm0.x = b1[k8+0]*TL2E; Cm0.y = b1[k8+1]*TL2E; Cm0.z = b1[k8+2]*TL2E; Cm0.w = b1[k8+3]*TL2E;
  Cm1.x = b1[k8+4]*TL2E; Cm1.y = b1[k8+5]*TL2E; Cm1.z = b1[k8+6]*TL2E; Cm1.w = b1[k8+7]*TL2E;
  Ct0.x = gb1[k8+0]*TL2E; Ct0.y = gb1[k8+1]*TL2E; Ct0.z = gb1[k8+2]*TL2E; Ct0.w = gb1[k8+3]*TL2E;
  Ct1.x = gb1[k8+4]*TL2E; Ct1.y = gb1[k8+5]*TL2E; Ct1.z = gb1[k8+6]*TL2E; Ct1.w = gb1[k8+7]*TL2E;
  C20.x = gb2p[k8+0]; C20.y = gb2p[k8+1]; C20.z = gb2p[k8+2]; C20.w = gb2p[k8+3];
  C21.x = gb2p[k8+4]; C21.y = gb2p[k8+5]; C21.z = gb2p[k8+6]; C21.w = gb2p[k8+7];
  Cw2.x = cs2b2[0]; Cw2.y = cs2b2[1]; Cw2.z = cs2b2[2]; Cw2.w = cs2b2[3];
  Cg3.x = gb3p[0]; Cg3.y = gb3p[1]; Cg3.z = gb3p[2]; Cg3.w = gb3p[3];

  float4 yv0 = ((const float4*)y0)[sys];
  float y[4] = {yv0.x, yv0.y, yv0.z, yv0.w};
  {
    float s0 = (g == 0) ? y[0] : ((g == 1) ? y[1] : ((g == 2) ? y[2] : y[3]));
    out[(size_t)sys * 4 + g] = s0;
  }

  const bool g0 = (g == 0);
  const unsigned ONES = 0x3C003C00u;   // packed {1.0h, 1.0h}

  auto feval = [&](const float yv[4], float kv[4]) {
    unsigned yp0 = pkrtz(yv[0], yv[1]);
    unsigned yp1 = pkrtz(yv[2], yv[3]);
    uint4 bu;
    bu.x = g0 ? yp0 : 0u;
    bu.y = g0 ? yp1 : 0u;
    bu.z = 0u; bu.w = 0u;
    half8 Bf = h8(bu);
    f32x4 dm0 = MFMA(Am0, Bf, Cm0);
    f32x4 dm1 = MFMA(Am1, Bf, Cm1);
    f32x4 dt0 = MFMA(At0, Bf, Ct0);
    f32x4 dt1 = MFMA(At1, Bf, Ct1);

    // mag hidden r-values -> B frag for W2
    uint4 hb;
    hb.x = pkrtz(frf(dm0.x), frf(dm0.y));
    hb.y = pkrtz(frf(dm0.z), frf(dm0.w));
    hb.z = pkrtz(frf(dm1.x), frf(dm1.y));
    hb.w = pkrtz(frf(dm1.z), frf(dm1.w));
    f32x4 dmm = MFMA(Aw2, h8(hb), Cw2);

    // t: pack r early; stats via dot2; normalize via pk_fma_f16
    uint4 tb;
    tb.x = pkrtz(frf(dt0.x), frf(dt0.y));
    tb.y = pkrtz(frf(dt0.z), frf(dt0.w));
    tb.z = pkrtz(frf(dt1.x), frf(dt1.y));
    tb.w = pkrtz(frf(dt1.z), frf(dt1.w));
    {
      float S  = fdot2u(tb.w, ONES, fdot2u(tb.z, ONES,
                 fdot2u(tb.y, ONES, fdot2u(tb.x, ONES, 0.f))));
      float SS = fdot2u(tb.w, tb.w, fdot2u(tb.z, tb.z,
                 fdot2u(tb.y, tb.y, fdot2u(tb.x, tb.x, 0.f))));
      S += __shfl_xor(S, 16);  SS += __shfl_xor(SS, 16);
      S += __shfl_xor(S, 32);  SS += __shfl_xor(SS, 32);
      float m   = fmaf(-0.0625f, S, 1.0f);
      float Et2 = fmaf(0.125f, SS - S, 1.0f);
      float v   = fmaf(-m, m, Et2);
      float rr  = __frsqrt_rn(v + EPSV);
      float c1  = -2.0f * rr;
      float c0  = fmaf(-m, rr, rr);
      unsigned c1p = pkrtz(c1, c1), c0p = pkrtz(c0, c0);
      tb.x = pkfma16(tb.x, c1p, c0p);
      tb.y = pkfma16(tb.y, c1p, c0p);
      tb.z = pkfma16(tb.z, c1p, c0p);
      tb.w = pkfma16(tb.w, c1p, c0p);
    }
    f32x4 du0 = MFMA(A20, h8(tb), C20);
    f32x4 du1 = MFMA(A21, h8(tb), C21);

    // u: same r-packed LN
    uint4 ub;
    ub.x = pkrtz(frf(du0.x), frf(du0.y));
    ub.y = pkrtz(frf(du0.z), frf(du0.w));
    ub.z = pkrtz(frf(du1.x), frf(du1.y));
    ub.w = pkrtz(frf(du1.z), frf(du1.w));
    {
      float S  = fdot2u(ub.w, ONES, fdot2u(ub.z, ONES,
                 fdot2u(ub.y, ONES, fdot2u(ub.x, ONES, 0.f))));
      float SS = fdot2u(ub.w, ub.w, fdot2u(ub.z, ub.z,
                 fdot2u(ub.y, ub.y, fdot2u(ub.x, ub.x, 0.f))));
      S += __shfl_xor(S, 16);  SS += __shfl_xor(SS, 16);
      S += __shfl_xor(S, 32);  SS += __shfl_xor(SS, 32);
      float m   = fmaf(-0.0625f, S, 1.0f);
      float Et2 = fmaf(0.125f, SS - S, 1.0f);
      float v   = fmaf(-m, m, Et2);
      float rr  = __frsqrt_rn(v + EPSV);
      float c1  = -2.0f * rr;
      float c0  = fmaf(-m, rr, rr);
      unsigned c1p = pkrtz(c1, c1), c0p = pkrtz(c0, c0);
      ub.x = pkfma16(ub.x, c1p, c0p);
      ub.y = pkfma16(ub.y, c1p, c0p);
      ub.z = pkfma16(ub.z, c1p, c0p);
      ub.w = pkfma16(ub.w, c1p, c0p);
    }
    f32x4 dz = MFMA(Ag3, h8(ub), Cg3);

    float kq0 = dmm.x * __builtin_amdgcn_exp2f(NL2E * dz.x * dz.x);
    float kq1 = dmm.y * __builtin_amdgcn_exp2f(NL2E * dz.y * dz.y);
    float kq2 = dmm.z * __builtin_amdgcn_exp2f(NL2E * dz.z * dz.z);
    float kq3 = dmm.w * __builtin_amdgcn_exp2f(NL2E * dz.w * dz.w);
    kv[0] = __shfl(kq0, n);
    kv[1] = __shfl(kq1, n);
    kv[2] = __shfl(kq2, n);
    kv[3] = __shfl(kq3, n);
  };

  #pragma unroll 1
  for (int t = 0; t < T - 1; ++t) {
    const float h = sg[t + 1] - sg[t];
    float k[4], ksum[4], yt[4];

    feval(y, k);
    #pragma unroll
    for (int c = 0; c < 4; ++c) { ksum[c] = k[c]; yt[c] = fmaf(0.5f * h, k[c], y[c]); }
    feval(yt, k);
    #pragma unroll
    for (int c = 0; c < 4; ++c) { ksum[c] = fmaf(2.0f, k[c], ksum[c]); yt[c] = fmaf(0.5f * h, k[c], y[c]); }
    feval(yt, k);
    #pragma unroll
    for (int c = 0; c < 4; ++c) { ksum[c] = fmaf(2.0f, k[c], ksum[c]); yt[c] = fmaf(h, k[c], y[c]); }
    feval(yt, k);
    #pragma unroll
    for (int c = 0; c < 4; ++c)
      y[c] = fmaf(h * (1.0f / 6.0f), ksum[c] + k[c], y[c]);

    float s0 = (g == 0) ? y[0] : ((g == 1) ? y[1] : ((g == 2) ? y[2] : y[3]));
    out[(size_t)(t + 1) * 4 * B + (size_t)sys * 4 + g] = s0;
  }
}

extern "C" void kernel_launch(void* const* d_in, const int* in_sizes, int n_in,
                              void* d_out, int out_size, void* d_ws, size_t ws_size,
                              hipStream_t stream) {
  const float* s_grid = (const float*)d_in[0];
  const float* y0     = (const float*)d_in[1];
  const float* W1     = (const float*)d_in[2];
  const float* b1     = (const float*)d_in[3];
  const float* W2     = (const float*)d_in[4];
  const float* b2     = (const float*)d_in[5];
  const float* G1     = (const float*)d_in[6];
  const float* gb1    = (const float*)d_in[7];
  const float* l1g    = (const float*)d_in[8];
  const float* l1b    = (const float*)d_in[9];
  const float* G2     = (const float*)d_in[10];
  const float* gb2    = (const float*)d_in[11];
  const float* l2g    = (const float*)d_in[12];
  const float* l2b    = (const float*)d_in[13];
  const float* G3     = (const float*)d_in[14];
  const float* gb3    = (const float*)d_in[15];

  const int T = in_sizes[0];
  const int B = in_sizes[1] / 4;

  const long long threads = 4LL * B;   // 4 row-group lanes per system
  dim3 block(256);
  dim3 grid((unsigned)((threads + 255) / 256));
  hipLaunchKernelGGL(ode_kernel, grid, block, 0, stream,
                     s_grid, y0, W1, b1, W2, b2, G1, gb1, l1g, l1b,
                     G2, gb2, l2g, l2b, G3, gb3, (float*)d_out, T, B);
}